// Round 4
// baseline (712.090 us; speedup 1.0000x reference)
//
#include <hip/hip_runtime.h>

#define B_ 4
#define L_ 2000
#define LP 2048       // padded length for Q/K/V buffers
#define C_ 512
#define H_ 8
#define HD 64
#define CHUNK_ 1000

typedef __attribute__((ext_vector_type(8))) short bf16x8;
typedef __attribute__((ext_vector_type(4))) float f32x4;

__device__ inline unsigned short f2bf(float f) {
    union { float f; unsigned int u; } v; v.f = f;
    unsigned int r = v.u + 0x7fffu + ((v.u >> 16) & 1u);
    return (unsigned short)(r >> 16);
}

// -------------------------------------------------------------------------
// conv (depthwise k=3, zero pad at 1000-chunk boundaries) + residual + bias,
// bf16 out; also emits x cast to bf16. Vectorized x4 over channels.
// -------------------------------------------------------------------------
__global__ void conv_kernel(const float* __restrict__ x, const float* __restrict__ Wl,
                            const float* __restrict__ bl,
                            unsigned short* __restrict__ kv16,
                            unsigned short* __restrict__ x16) {
    int i4 = blockIdx.x * 256 + threadIdx.x;
    if (i4 >= B_ * L_ * C_ / 4) return;
    int idx = i4 * 4;
    int c = idx & (C_ - 1);
    int l = (idx >> 9) % L_;
    int p = l % CHUNK_;
    float4 xc = *(const float4*)&x[idx];
    float4 lf = (p > 0)          ? *(const float4*)&x[idx - C_] : make_float4(0, 0, 0, 0);
    float4 rt = (p < CHUNK_ - 1) ? *(const float4*)&x[idx + C_] : make_float4(0, 0, 0, 0);
    float y[4];
    const float* xcp = &xc.x; const float* lfp = &lf.x; const float* rtp = &rt.x;
#pragma unroll
    for (int j = 0; j < 4; j++) {
        y[j] = xcp[j] + bl[c + j] + Wl[(c + j) * 3 + 0] * lfp[j]
             + Wl[(c + j) * 3 + 1] * xcp[j] + Wl[(c + j) * 3 + 2] * rtp[j];
    }
    ushort4 kv = make_ushort4(f2bf(y[0]), f2bf(y[1]), f2bf(y[2]), f2bf(y[3]));
    ushort4 xo = make_ushort4(f2bf(xcp[0]), f2bf(xcp[1]), f2bf(xcp[2]), f2bf(xcp[3]));
    *(ushort4*)&kv16[idx] = kv;
    *(ushort4*)&x16[idx]  = xo;
}

// Both weight tensors cast in one launch (x4 vectorized).
__global__ void cvt_kernel(const float* __restrict__ Wq, const float* __restrict__ Wkv,
                           unsigned short* __restrict__ Wq16,
                           unsigned short* __restrict__ Wkv16) {
    int i4 = blockIdx.x * 256 + threadIdx.x;
    int idx = i4 * 4;
    const float* src; unsigned short* dst; int off;
    if (idx < 262144) { src = Wq; dst = Wq16; off = idx; }
    else if (idx < 786432) { src = Wkv; dst = Wkv16; off = idx - 262144; }
    else return;
    float4 v = *(const float4*)&src[off];
    *(ushort4*)&dst[off] = make_ushort4(f2bf(v.x), f2bf(v.y), f2bf(v.z), f2bf(v.w));
}

// -------------------------------------------------------------------------
// Projection GEMM via MFMA, LDS-staged coalesced epilogue.
// A:[8000][512] bf16, W:[N][512] bf16. Block: 4 waves, 64m x 64n tile.
// mode 0: Q -> [bh][2048][64]. mode 1: by<8 -> K [bh][2048][64];
//         by>=8 -> V transposed [bh][64][2048] (LDS transpose, row stores).
// -------------------------------------------------------------------------
__global__ __launch_bounds__(256) void proj_mfma(
    const unsigned short* __restrict__ A, const unsigned short* __restrict__ W,
    const float* __restrict__ bias,
    unsigned short* __restrict__ o0, unsigned short* __restrict__ o1, int mode) {
    __shared__ __align__(16) unsigned short tile[64][72];
    const int tid = threadIdx.x;
    const int lane = tid & 63;
    const int wave = tid >> 6;
    const int c = lane & 15;
    const int quad = lane >> 4;
    const int mrow = blockIdx.x * 64 + wave * 16 + c;
    const int n0 = blockIdx.y * 64;
    f32x4 acc[4] = {{0,0,0,0},{0,0,0,0},{0,0,0,0},{0,0,0,0}};
    const unsigned short* Ap = A + (size_t)mrow * C_ + quad * 8;
#pragma unroll 4
    for (int k0 = 0; k0 < C_; k0 += 32) {
        bf16x8 a = *(const bf16x8*)(Ap + k0);
#pragma unroll
        for (int t = 0; t < 4; t++) {
            bf16x8 wv = *(const bf16x8*)&W[(size_t)(n0 + 16 * t + c) * C_ + k0 + quad * 8];
            acc[t] = __builtin_amdgcn_mfma_f32_16x16x32_bf16(a, wv, acc[t], 0, 0, 0);
        }
    }
    const bool vpath = (mode == 1 && n0 >= C_);
    const int lm = wave * 16 + quad * 4;
#pragma unroll
    for (int t = 0; t < 4; t++) {
        float bv = bias[n0 + 16 * t + c];
#pragma unroll
        for (int r = 0; r < 4; r++) {
            unsigned short val = f2bf(acc[t][r] + bv);
            if (!vpath) tile[lm + r][16 * t + c] = val;   // [m][n]
            else        tile[16 * t + c][lm + r] = val;   // [n][m] transpose
        }
    }
    __syncthreads();
    if (!vpath) {
        int lr = tid >> 2, chunk = (tid & 3) * 16;
        int m = blockIdx.x * 64 + lr;
        int b = m / L_, l = m % L_;
        int nn = (n0 + chunk) & (C_ - 1);
        int h = nn >> 6, d0 = nn & 63;
        unsigned short* dst = &o0[(((size_t)(b * H_ + h) * LP) + l) * HD + d0];
        *(uint4*)dst       = *(const uint4*)&tile[lr][chunk];
        *(uint4*)(dst + 8) = *(const uint4*)&tile[lr][chunk + 8];
    } else {
        int dr = tid >> 2, chunk = (tid & 3) * 16;
        int nn = (n0 - C_) + dr;
        int h = nn >> 6, d = nn & 63;
        int mbase = blockIdx.x * 64 + chunk;
        int b0 = mbase / L_, b1 = (mbase + 15) / L_;
        if (b0 == b1) {
            int l = mbase % L_;
            unsigned short* dst = &o1[(((size_t)(b0 * H_ + h) * HD) + d) * LP + l];
            *(uint4*)dst       = *(const uint4*)&tile[dr][chunk];
            *(uint4*)(dst + 8) = *(const uint4*)&tile[dr][chunk + 8];
        } else {
            for (int i = 0; i < 16; i++) {
                int m = mbase + i;
                int b = m / L_, l = m % L_;
                o1[(((size_t)(b * H_ + h) * HD) + d) * LP + l] = tile[dr][chunk + i];
            }
        }
    }
}

// -------------------------------------------------------------------------
// Flash attention, bf16 MFMA. ONE BLOCK = ALL 4 BATCHES of (h, 64-row tile,
// K-half). ROUND-3 (resubmitted round 4 after infra failure): proven LDS
// K/V staging (bulk coalesced staging = ~16x fewer L1/TA segments than
// per-fragment global loads, the round-1 regression), plus two levers:
//  (1) TRANSPOSED-S MFMA: s^T = mfma(K_frag, Q_frag). C-layout flips so a
//      lane's 8 logits live at ONE q-row (r0w+c), 4 consecutive k-cols
//      -> rpe = 2 float4 loads/wave-iter (was 8 scattered dwords), row
//      pointer hoisted (no per-iter 64-bit addr chains), Ps write = 2
//      ds_write_b64 (was 8 ds_write_b16), l-reduce = 2 shuffles (was 16).
//  (2) 4-DEEP rpe register ring (32 VGPR): outstanding rpe per wave
//      2KB -> 8KB, lifting the Little's-law ~450 GB/s rpe-stream ceiling.
// -------------------------------------------------------------------------
__global__ __launch_bounds__(256, 2) void attn_mfma(
    const unsigned short* __restrict__ Q, const unsigned short* __restrict__ K,
    const unsigned short* __restrict__ Vt, const float* __restrict__ rpe,
    float* __restrict__ po, float* __restrict__ lsum) {
    __shared__ __align__(16) unsigned short Ks[4][32][72];   // [b][s-col][k=64+pad]
    __shared__ __align__(16) unsigned short Vs[4][64][40];   // [b][d][l=32+pad]
    __shared__ __align__(16) unsigned short Ps[4][2][16][40];// [wave][b&1][qrow][kcol]
    const int tid = threadIdx.x;
    const int lane = tid & 63;
    const int wave = tid >> 6;
    const int c = lane & 15;
    const int quad = lane >> 4;
    const int bid = blockIdx.x;
    const int ks = bid & 1;
    const int h  = (bid >> 1) & 7;
    const int rt = bid >> 4;
    const int r0w = rt * 64 + wave * 16;
    const int rg0 = r0w + quad * 4;        // o_acc row base (epilogue)
    // per-lane rpe row pointer (row = r0w + c, clamped; hoisted 64-bit math)
    const int rgc = min(r0w + c, L_ - 1);
    const float* rrow = rpe + (size_t)h * L_ * L_ + (size_t)rgc * L_;

    // staging coords: K tile [32 rows][64 k] (128B rows), V tile [64 d][32 l]
    const int krow = tid >> 3, kcol = (tid & 7) * 8;
    const int vrow = tid >> 2, vcol = (tid & 3) * 8;

    bf16x8 qf0[4], qf1[4];
    const unsigned short* Kp[4];
    const unsigned short* Vp[4];
    const int kt0 = ks * 32, kt1 = kt0 + 32;
#pragma unroll
    for (int b = 0; b < 4; b++) {
        const unsigned short* Qb = Q + (size_t)(b * H_ + h) * LP * HD;
        qf0[b] = *(const bf16x8*)&Qb[(size_t)(r0w + c) * HD + quad * 8];
        qf1[b] = *(const bf16x8*)&Qb[(size_t)(r0w + c) * HD + 32 + quad * 8];
        Kp[b] = K  + (size_t)(b * H_ + h) * LP * HD + (size_t)krow * HD + kcol
                  + (size_t)(kt0 * 32) * HD;
        Vp[b] = Vt + (size_t)(b * H_ + h) * HD * LP + (size_t)vrow * LP + vcol
                  + kt0 * 32;
    }

    float l_i[4] = {0.f, 0.f, 0.f, 0.f};
    f32x4 o_acc[4][4];
#pragma unroll
    for (int b = 0; b < 4; b++)
#pragma unroll
        for (int t = 0; t < 4; t++) o_acc[b][t] = (f32x4){0.f, 0.f, 0.f, 0.f};

    // ---- rpe loader: cols kt*32 + 16t + quad*4 .. +3 at fixed row ----
    const float LOG2E = 1.44269504f;
#define LOAD_RPE(dst, KT)                                                    \
    {                                                                        \
        _Pragma("unroll")                                                    \
        for (int t = 0; t < 2; t++) {                                        \
            int cb = (KT) * 32 + 16 * t + quad * 4;                          \
            int cbc = min(cb, L_ - 4);                                       \
            float4 raw = *(const float4*)&rrow[cbc];                         \
            bool cv = (cb <= L_ - 4);                                        \
            dst[t] = cv ? make_float4(raw.x * LOG2E, raw.y * LOG2E,          \
                                      raw.z * LOG2E, raw.w * LOG2E)         \
                        : make_float4(-1e30f, -1e30f, -1e30f, -1e30f);       \
        }                                                                    \
    }

    // ---- prologue: first K/V tiles + 4-deep rpe ring ----
    uint4 kpre[4], vpre[4];
    float4 rp[4][2];
#pragma unroll
    for (int b = 0; b < 4; b++) {
        kpre[b] = *(const uint4*)Kp[b];
        vpre[b] = *(const uint4*)Vp[b];
    }
#pragma unroll
    for (int u = 0; u < 4; u++) LOAD_RPE(rp[u], kt0 + u);

    for (int kt4 = kt0; kt4 < kt1; kt4 += 4) {
#pragma unroll
        for (int u = 0; u < 4; u++) {
            const int kt = kt4 + u;
            __syncthreads();   // all waves done with previous tiles
#pragma unroll
            for (int b = 0; b < 4; b++) {
                *(uint4*)&Ks[b][krow][kcol] = kpre[b];
                *(uint4*)&Vs[b][vrow][vcol] = vpre[b];
            }
            __syncthreads();   // tiles visible

            // prefetch next K/V tiles (consumed next iteration)
            if (kt + 1 < kt1) {
#pragma unroll
                for (int b = 0; b < 4; b++) {
                    Kp[b] += 32 * HD;
                    Vp[b] += 32;
                    kpre[b] = *(const uint4*)Kp[b];
                    vpre[b] = *(const uint4*)Vp[b];
                }
            }

            // ---- 4 per-batch chains ----
#pragma unroll
            for (int b = 0; b < 4; b++) {
                // S^T = K Q^T : lane holds logits for qrow=r0w+c,
                // kcols kt*32 + 16t + quad*4 + r
                f32x4 s[2];
#pragma unroll
                for (int t = 0; t < 2; t++) {
                    bf16x8 k0f = *(const bf16x8*)&Ks[b][16 * t + c][quad * 8];
                    bf16x8 k1f = *(const bf16x8*)&Ks[b][16 * t + c][32 + quad * 8];
                    f32x4 z = {0.f, 0.f, 0.f, 0.f};
                    z = __builtin_amdgcn_mfma_f32_16x16x32_bf16(k0f, qf0[b], z, 0, 0, 0);
                    z = __builtin_amdgcn_mfma_f32_16x16x32_bf16(k1f, qf1[b], z, 0, 0, 0);
                    s[t] = z;
                }
                // p = exp2(s*scale*log2e + rpe*log2e); P^T -> Ps (packed b64)
                float psum = 0.f;
#pragma unroll
                for (int t = 0; t < 2; t++) {
                    const float* rpt = &rp[u][t].x;
                    float p0 = exp2f(fmaf(s[t][0], 0.18033688f, rpt[0]));
                    float p1 = exp2f(fmaf(s[t][1], 0.18033688f, rpt[1]));
                    float p2 = exp2f(fmaf(s[t][2], 0.18033688f, rpt[2]));
                    float p3 = exp2f(fmaf(s[t][3], 0.18033688f, rpt[3]));
                    psum += (p0 + p1) + (p2 + p3);
                    *(ushort4*)&Ps[wave][b & 1][c][16 * t + quad * 4] =
                        make_ushort4(f2bf(p0), f2bf(p1), f2bf(p2), f2bf(p3));
                }
                l_i[b] += psum;
                // O += P V : K-dim 32, one MFMA per d-tile
                bf16x8 pa = *(const bf16x8*)&Ps[wave][b & 1][c][quad * 8];
#pragma unroll
                for (int t = 0; t < 4; t++) {
                    bf16x8 v0 = *(const bf16x8*)&Vs[b][16 * t + c][quad * 8];
                    o_acc[b][t] = __builtin_amdgcn_mfma_f32_16x16x32_bf16(pa, v0, o_acc[b][t], 0, 0, 0);
                }
            }
            // refill rpe ring slot (consumed this iter) for kt+4
            if (kt + 4 < kt1) LOAD_RPE(rp[u], kt + 4);
        }
    }

    // ---- epilogue: reduce l over quads; store raw partials ----
#pragma unroll
    for (int b = 0; b < 4; b++) {
        float v = l_i[b];
        v += __shfl_xor(v, 16);
        v += __shfl_xor(v, 32);
        float* pob = po + (size_t)(ks * 32 + b * H_ + h) * L_ * HD;
#pragma unroll
        for (int t = 0; t < 4; t++) {
            int d = 16 * t + c;
#pragma unroll
            for (int r = 0; r < 4; r++) {
                int l = rg0 + r;
                if (l < L_) pob[(size_t)l * HD + d] = o_acc[b][t][r];
            }
        }
        if (lane < 16) {
            float* lb = lsum + (size_t)(ks * 32 + b * H_ + h) * LP;
            lb[r0w + lane] = v;
        }
    }
#undef LOAD_RPE
}

// -------------------------------------------------------------------------
// Merge: out[bh][d][l] = (po0+po1)[bh][l][d] / (l0+l1)[bh][l], LDS transpose.
// -------------------------------------------------------------------------
__global__ __launch_bounds__(256) void merge_kernel(
    const float* __restrict__ po, const float* __restrict__ lsum,
    float* __restrict__ out) {
    __shared__ __align__(16) float T[64][68];
    const int tid = threadIdx.x;
    const int bh = blockIdx.x >> 5;
    const int lt = blockIdx.x & 31;
    const float* p0 = po + (size_t)bh * L_ * HD;
    const float* p1 = p0 + (size_t)32 * L_ * HD;
    const float* ls0 = lsum + (size_t)bh * LP;
    const float* ls1 = ls0 + (size_t)32 * LP;
#pragma unroll
    for (int it = 0; it < 4; it++) {
        int idx = it * 256 + tid;
        int row = idx >> 4;
        int dc = (idx & 15) * 4;
        int l = lt * 64 + row;
        float4 v = make_float4(0.f, 0.f, 0.f, 0.f);
        if (l < L_) {
            float4 a  = *(const float4*)&p0[(size_t)l * HD + dc];
            float4 b4 = *(const float4*)&p1[(size_t)l * HD + dc];
            float inv = 1.f / (ls0[l] + ls1[l]);
            v = make_float4((a.x + b4.x) * inv, (a.y + b4.y) * inv,
                            (a.z + b4.z) * inv, (a.w + b4.w) * inv);
        }
        T[dc + 0][row] = v.x; T[dc + 1][row] = v.y;
        T[dc + 2][row] = v.z; T[dc + 3][row] = v.w;
    }
    __syncthreads();
    const int d = tid >> 2, ch = (tid & 3) * 16;
    const int lbase = lt * 64 + ch;
    if (lbase + 15 < L_) {
        float* dst = &out[((size_t)(bh * HD + d)) * L_ + lbase];
#pragma unroll
        for (int i = 0; i < 4; i++)
            *(float4*)&dst[4 * i] = *(const float4*)&T[d][ch + 4 * i];
    }
}

extern "C" void kernel_launch(void* const* d_in, const int* in_sizes, int n_in,
                              void* d_out, int out_size, void* d_ws, size_t ws_size,
                              hipStream_t stream) {
    const float* x   = (const float*)d_in[0];
    const float* rpe = (const float*)d_in[1];
    const float* Wq  = (const float*)d_in[2];
    const float* bq  = (const float*)d_in[3];
    const float* Wkv = (const float*)d_in[4];
    const float* bkv = (const float*)d_in[5];
    const float* Wl  = (const float*)d_in[6];
    const float* bl  = (const float*)d_in[7];
    float* out = (float*)d_out;

    unsigned short* wsu  = (unsigned short*)d_ws;
    unsigned short* x16  = wsu;                 // 4,096,000
    unsigned short* kv16 = wsu + 4096000;       // 4,096,000
    unsigned short* Wq16 = wsu + 8192000;       //   262,144
    unsigned short* Wkv16= wsu + 8454144;       //   524,288
    unsigned short* Q16  = wsu + 8978432;       // 4,194,304  [bh][2048][64]
    unsigned short* K16  = wsu + 13172736;      // 4,194,304  [bh][2048][64]
    unsigned short* V16  = wsu + 17367040;      // 4,194,304  [bh][64][2048]
    float* po   = (float*)(wsu + 21561344);     // 8,192,000 fp32 [2][32][2000][64]
    float* lsum = po + 8192000;                 //   131,072 fp32 [2][32][2048]

    conv_kernel<<<(B_ * L_ * C_ / 4 + 255) / 256, 256, 0, stream>>>(x, Wl, bl, kv16, x16);
    cvt_kernel<<<(786432 / 4 + 255) / 256, 256, 0, stream>>>(Wq, Wkv, Wq16, Wkv16);
    proj_mfma<<<dim3(125, 8), 256, 0, stream>>>(x16, Wq16, bq, Q16, nullptr, 0);
    proj_mfma<<<dim3(125, 16), 256, 0, stream>>>(kv16, Wkv16, bkv, K16, V16, 1);
    attn_mfma<<<512, 256, 0, stream>>>(Q16, K16, V16, rpe, po, lsum);
    merge_kernel<<<1024, 256, 0, stream>>>(po, lsum, out);
}

// Round 5
// 596.539 us; speedup vs baseline: 1.1937x; 1.1937x over previous
//
#include <hip/hip_runtime.h>

#define B_ 4
#define L_ 2000
#define LP 2048       // padded length for Q/K/V buffers
#define C_ 512
#define H_ 8
#define HD 64
#define CHUNK_ 1000

typedef __attribute__((ext_vector_type(8))) short bf16x8;
typedef __attribute__((ext_vector_type(4))) float f32x4;

__device__ inline unsigned short f2bf(float f) {
    union { float f; unsigned int u; } v; v.f = f;
    unsigned int r = v.u + 0x7fffu + ((v.u >> 16) & 1u);
    return (unsigned short)(r >> 16);
}

// -------------------------------------------------------------------------
// conv (depthwise k=3, zero pad at 1000-chunk boundaries) + residual + bias,
// bf16 out; also emits x cast to bf16. Vectorized x4 over channels.
// -------------------------------------------------------------------------
__global__ void conv_kernel(const float* __restrict__ x, const float* __restrict__ Wl,
                            const float* __restrict__ bl,
                            unsigned short* __restrict__ kv16,
                            unsigned short* __restrict__ x16) {
    int i4 = blockIdx.x * 256 + threadIdx.x;
    if (i4 >= B_ * L_ * C_ / 4) return;
    int idx = i4 * 4;
    int c = idx & (C_ - 1);
    int l = (idx >> 9) % L_;
    int p = l % CHUNK_;
    float4 xc = *(const float4*)&x[idx];
    float4 lf = (p > 0)          ? *(const float4*)&x[idx - C_] : make_float4(0, 0, 0, 0);
    float4 rt = (p < CHUNK_ - 1) ? *(const float4*)&x[idx + C_] : make_float4(0, 0, 0, 0);
    float y[4];
    const float* xcp = &xc.x; const float* lfp = &lf.x; const float* rtp = &rt.x;
#pragma unroll
    for (int j = 0; j < 4; j++) {
        y[j] = xcp[j] + bl[c + j] + Wl[(c + j) * 3 + 0] * lfp[j]
             + Wl[(c + j) * 3 + 1] * xcp[j] + Wl[(c + j) * 3 + 2] * rtp[j];
    }
    ushort4 kv = make_ushort4(f2bf(y[0]), f2bf(y[1]), f2bf(y[2]), f2bf(y[3]));
    ushort4 xo = make_ushort4(f2bf(xcp[0]), f2bf(xcp[1]), f2bf(xcp[2]), f2bf(xcp[3]));
    *(ushort4*)&kv16[idx] = kv;
    *(ushort4*)&x16[idx]  = xo;
}

// Both weight tensors cast in one launch (x4 vectorized).
__global__ void cvt_kernel(const float* __restrict__ Wq, const float* __restrict__ Wkv,
                           unsigned short* __restrict__ Wq16,
                           unsigned short* __restrict__ Wkv16) {
    int i4 = blockIdx.x * 256 + threadIdx.x;
    int idx = i4 * 4;
    const float* src; unsigned short* dst; int off;
    if (idx < 262144) { src = Wq; dst = Wq16; off = idx; }
    else if (idx < 786432) { src = Wkv; dst = Wkv16; off = idx - 262144; }
    else return;
    float4 v = *(const float4*)&src[off];
    *(ushort4*)&dst[off] = make_ushort4(f2bf(v.x), f2bf(v.y), f2bf(v.z), f2bf(v.w));
}

// -------------------------------------------------------------------------
// Projection GEMM via MFMA, LDS-staged coalesced epilogue.
// A:[8000][512] bf16, W:[N][512] bf16. Block: 4 waves, 64m x 64n tile.
// mode 0: Q -> [bh][2048][64]. mode 1: by<8 -> K [bh][2048][64];
//         by>=8 -> V transposed [bh][64][2048] (LDS transpose, row stores).
// -------------------------------------------------------------------------
__global__ __launch_bounds__(256) void proj_mfma(
    const unsigned short* __restrict__ A, const unsigned short* __restrict__ W,
    const float* __restrict__ bias,
    unsigned short* __restrict__ o0, unsigned short* __restrict__ o1, int mode) {
    __shared__ __align__(16) unsigned short tile[64][72];
    const int tid = threadIdx.x;
    const int lane = tid & 63;
    const int wave = tid >> 6;
    const int c = lane & 15;
    const int quad = lane >> 4;
    const int mrow = blockIdx.x * 64 + wave * 16 + c;
    const int n0 = blockIdx.y * 64;
    f32x4 acc[4] = {{0,0,0,0},{0,0,0,0},{0,0,0,0},{0,0,0,0}};
    const unsigned short* Ap = A + (size_t)mrow * C_ + quad * 8;
#pragma unroll 4
    for (int k0 = 0; k0 < C_; k0 += 32) {
        bf16x8 a = *(const bf16x8*)(Ap + k0);
#pragma unroll
        for (int t = 0; t < 4; t++) {
            bf16x8 wv = *(const bf16x8*)&W[(size_t)(n0 + 16 * t + c) * C_ + k0 + quad * 8];
            acc[t] = __builtin_amdgcn_mfma_f32_16x16x32_bf16(a, wv, acc[t], 0, 0, 0);
        }
    }
    const bool vpath = (mode == 1 && n0 >= C_);
    const int lm = wave * 16 + quad * 4;
#pragma unroll
    for (int t = 0; t < 4; t++) {
        float bv = bias[n0 + 16 * t + c];
#pragma unroll
        for (int r = 0; r < 4; r++) {
            unsigned short val = f2bf(acc[t][r] + bv);
            if (!vpath) tile[lm + r][16 * t + c] = val;   // [m][n]
            else        tile[16 * t + c][lm + r] = val;   // [n][m] transpose
        }
    }
    __syncthreads();
    if (!vpath) {
        int lr = tid >> 2, chunk = (tid & 3) * 16;
        int m = blockIdx.x * 64 + lr;
        int b = m / L_, l = m % L_;
        int nn = (n0 + chunk) & (C_ - 1);
        int h = nn >> 6, d0 = nn & 63;
        unsigned short* dst = &o0[(((size_t)(b * H_ + h) * LP) + l) * HD + d0];
        *(uint4*)dst       = *(const uint4*)&tile[lr][chunk];
        *(uint4*)(dst + 8) = *(const uint4*)&tile[lr][chunk + 8];
    } else {
        int dr = tid >> 2, chunk = (tid & 3) * 16;
        int nn = (n0 - C_) + dr;
        int h = nn >> 6, d = nn & 63;
        int mbase = blockIdx.x * 64 + chunk;
        int b0 = mbase / L_, b1 = (mbase + 15) / L_;
        if (b0 == b1) {
            int l = mbase % L_;
            unsigned short* dst = &o1[(((size_t)(b0 * H_ + h) * HD) + d) * LP + l];
            *(uint4*)dst       = *(const uint4*)&tile[dr][chunk];
            *(uint4*)(dst + 8) = *(const uint4*)&tile[dr][chunk + 8];
        } else {
            for (int i = 0; i < 16; i++) {
                int m = mbase + i;
                int b = m / L_, l = m % L_;
                o1[(((size_t)(b * H_ + h) * HD) + d) * LP + l] = tile[dr][chunk + i];
            }
        }
    }
}

// -------------------------------------------------------------------------
// Flash attention, bf16 MFMA. ONE BLOCK = ALL 4 BATCHES of (h, 64-row tile,
// K-half). ROUND-5: round-4's 4-deep rpe ring + deep prefetch blew the
// register budget (WRITE_SIZE 731MB = ~700MB scratch spills). Revert to the
// PROVEN 2-deep rpl/rpn double-buffer + 1-deep K/V register prefetch
// (prev-session schedule: VGPR=108, zero spill, 251us), keeping the one
// new lever:
//  TRANSPOSED-S MFMA: s^T = mfma(K_frag, Q_frag). C-layout flips so a
//  lane's 8 logits live at ONE q-row (r0w+c), 4 consecutive k-cols
//  -> rpe = 2 float4 loads/wave-iter off a hoisted row pointer (no
//  per-iter 64-bit addr chains), Ps write = 2 ds_write_b64 (was 8
//  ds_write_b16), l-reduce = 2 shuffles (was 16).
// -------------------------------------------------------------------------
__global__ __launch_bounds__(256, 2) void attn_mfma(
    const unsigned short* __restrict__ Q, const unsigned short* __restrict__ K,
    const unsigned short* __restrict__ Vt, const float* __restrict__ rpe,
    float* __restrict__ po, float* __restrict__ lsum) {
    __shared__ __align__(16) unsigned short Ks[4][32][72];   // [b][s-col][k=64+pad]
    __shared__ __align__(16) unsigned short Vs[4][64][40];   // [b][d][l=32+pad]
    __shared__ __align__(16) unsigned short Ps[4][2][16][40];// [wave][b&1][qrow][kcol]
    const int tid = threadIdx.x;
    const int lane = tid & 63;
    const int wave = tid >> 6;
    const int c = lane & 15;
    const int quad = lane >> 4;
    const int bid = blockIdx.x;
    const int ks = bid & 1;
    const int h  = (bid >> 1) & 7;
    const int rt = bid >> 4;
    const int r0w = rt * 64 + wave * 16;
    const int rg0 = r0w + quad * 4;        // o_acc row base (epilogue)
    // per-lane rpe row pointer (row = r0w + c, clamped; hoisted 64-bit math)
    const int rgc = min(r0w + c, L_ - 1);
    const float* rrow = rpe + (size_t)h * L_ * L_ + (size_t)rgc * L_;

    // staging coords: K tile [32 rows][64 k] (128B rows), V tile [64 d][32 l]
    const int krow = tid >> 3, kcol = (tid & 7) * 8;
    const int vrow = tid >> 2, vcol = (tid & 3) * 8;

    bf16x8 qf0[4], qf1[4];
    const unsigned short* Kp[4];
    const unsigned short* Vp[4];
    const int kt0 = ks * 32, kt1 = kt0 + 32;
#pragma unroll
    for (int b = 0; b < 4; b++) {
        const unsigned short* Qb = Q + (size_t)(b * H_ + h) * LP * HD;
        qf0[b] = *(const bf16x8*)&Qb[(size_t)(r0w + c) * HD + quad * 8];
        qf1[b] = *(const bf16x8*)&Qb[(size_t)(r0w + c) * HD + 32 + quad * 8];
        Kp[b] = K  + (size_t)(b * H_ + h) * LP * HD + (size_t)krow * HD + kcol
                  + (size_t)(kt0 * 32) * HD;
        Vp[b] = Vt + (size_t)(b * H_ + h) * HD * LP + (size_t)vrow * LP + vcol
                  + kt0 * 32;
    }

    float l_i[4] = {0.f, 0.f, 0.f, 0.f};
    f32x4 o_acc[4][4];
#pragma unroll
    for (int b = 0; b < 4; b++)
#pragma unroll
        for (int t = 0; t < 4; t++) o_acc[b][t] = (f32x4){0.f, 0.f, 0.f, 0.f};

    // ---- rpe loader: cols kt*32 + 16t + quad*4 .. +3 at fixed row ----
    const float LOG2E = 1.44269504f;
#define LOAD_RPE(dst, KT)                                                    \
    {                                                                        \
        _Pragma("unroll")                                                    \
        for (int t = 0; t < 2; t++) {                                        \
            int cb = (KT) * 32 + 16 * t + quad * 4;                          \
            int cbc = min(cb, L_ - 4);                                       \
            float4 raw = *(const float4*)&rrow[cbc];                         \
            bool cv = (cb <= L_ - 4);                                        \
            dst[t] = cv ? make_float4(raw.x * LOG2E, raw.y * LOG2E,          \
                                      raw.z * LOG2E, raw.w * LOG2E)         \
                        : make_float4(-1e30f, -1e30f, -1e30f, -1e30f);       \
        }                                                                    \
    }

    // ---- prologue: first K/V tiles + first rpe tile ----
    uint4 kpre[4], vpre[4];
    float4 rpl[2];
#pragma unroll
    for (int b = 0; b < 4; b++) {
        kpre[b] = *(const uint4*)Kp[b];
        vpre[b] = *(const uint4*)Vp[b];
    }
    LOAD_RPE(rpl, kt0)

    for (int kt = kt0; kt < kt1; kt++) {
        __syncthreads();   // all waves done with previous tiles
#pragma unroll
        for (int b = 0; b < 4; b++) {
            *(uint4*)&Ks[b][krow][kcol] = kpre[b];
            *(uint4*)&Vs[b][vrow][vcol] = vpre[b];
        }
        __syncthreads();   // tiles visible

        // prefetch next K/V tiles + next rpe (consumed next iteration)
        float4 rpn[2];
        if (kt + 1 < kt1) {
#pragma unroll
            for (int b = 0; b < 4; b++) {
                Kp[b] += 32 * HD;
                Vp[b] += 32;
                kpre[b] = *(const uint4*)Kp[b];
                vpre[b] = *(const uint4*)Vp[b];
            }
            LOAD_RPE(rpn, kt + 1)
        }

        // ---- 4 per-batch chains ----
#pragma unroll
        for (int b = 0; b < 4; b++) {
            // S^T = K Q^T : lane holds logits for qrow=r0w+c,
            // kcols kt*32 + 16t + quad*4 + r
            f32x4 s[2];
#pragma unroll
            for (int t = 0; t < 2; t++) {
                bf16x8 k0f = *(const bf16x8*)&Ks[b][16 * t + c][quad * 8];
                bf16x8 k1f = *(const bf16x8*)&Ks[b][16 * t + c][32 + quad * 8];
                f32x4 z = {0.f, 0.f, 0.f, 0.f};
                z = __builtin_amdgcn_mfma_f32_16x16x32_bf16(k0f, qf0[b], z, 0, 0, 0);
                z = __builtin_amdgcn_mfma_f32_16x16x32_bf16(k1f, qf1[b], z, 0, 0, 0);
                s[t] = z;
            }
            // p = exp2(s*scale*log2e + rpe*log2e); P^T -> Ps (packed b64)
            float psum = 0.f;
#pragma unroll
            for (int t = 0; t < 2; t++) {
                const float* rpt = &rpl[t].x;
                float p0 = exp2f(fmaf(s[t][0], 0.18033688f, rpt[0]));
                float p1 = exp2f(fmaf(s[t][1], 0.18033688f, rpt[1]));
                float p2 = exp2f(fmaf(s[t][2], 0.18033688f, rpt[2]));
                float p3 = exp2f(fmaf(s[t][3], 0.18033688f, rpt[3]));
                psum += (p0 + p1) + (p2 + p3);
                *(ushort4*)&Ps[wave][b & 1][c][16 * t + quad * 4] =
                    make_ushort4(f2bf(p0), f2bf(p1), f2bf(p2), f2bf(p3));
            }
            l_i[b] += psum;
            // O += P V : K-dim 32, one MFMA per d-tile
            bf16x8 pa = *(const bf16x8*)&Ps[wave][b & 1][c][quad * 8];
#pragma unroll
            for (int t = 0; t < 4; t++) {
                bf16x8 v0 = *(const bf16x8*)&Vs[b][16 * t + c][quad * 8];
                o_acc[b][t] = __builtin_amdgcn_mfma_f32_16x16x32_bf16(pa, v0, o_acc[b][t], 0, 0, 0);
            }
        }
        if (kt + 1 < kt1) { rpl[0] = rpn[0]; rpl[1] = rpn[1]; }
    }

    // ---- epilogue: reduce l over quads; store raw partials ----
#pragma unroll
    for (int b = 0; b < 4; b++) {
        float v = l_i[b];
        v += __shfl_xor(v, 16);
        v += __shfl_xor(v, 32);
        float* pob = po + (size_t)(ks * 32 + b * H_ + h) * L_ * HD;
#pragma unroll
        for (int t = 0; t < 4; t++) {
            int d = 16 * t + c;
#pragma unroll
            for (int r = 0; r < 4; r++) {
                int l = rg0 + r;
                if (l < L_) pob[(size_t)l * HD + d] = o_acc[b][t][r];
            }
        }
        if (lane < 16) {
            float* lb = lsum + (size_t)(ks * 32 + b * H_ + h) * LP;
            lb[r0w + lane] = v;
        }
    }
#undef LOAD_RPE
}

// -------------------------------------------------------------------------
// Merge: out[bh][d][l] = (po0+po1)[bh][l][d] / (l0+l1)[bh][l], LDS transpose.
// -------------------------------------------------------------------------
__global__ __launch_bounds__(256) void merge_kernel(
    const float* __restrict__ po, const float* __restrict__ lsum,
    float* __restrict__ out) {
    __shared__ __align__(16) float T[64][68];
    const int tid = threadIdx.x;
    const int bh = blockIdx.x >> 5;
    const int lt = blockIdx.x & 31;
    const float* p0 = po + (size_t)bh * L_ * HD;
    const float* p1 = p0 + (size_t)32 * L_ * HD;
    const float* ls0 = lsum + (size_t)bh * LP;
    const float* ls1 = ls0 + (size_t)32 * LP;
#pragma unroll
    for (int it = 0; it < 4; it++) {
        int idx = it * 256 + tid;
        int row = idx >> 4;
        int dc = (idx & 15) * 4;
        int l = lt * 64 + row;
        float4 v = make_float4(0.f, 0.f, 0.f, 0.f);
        if (l < L_) {
            float4 a  = *(const float4*)&p0[(size_t)l * HD + dc];
            float4 b4 = *(const float4*)&p1[(size_t)l * HD + dc];
            float inv = 1.f / (ls0[l] + ls1[l]);
            v = make_float4((a.x + b4.x) * inv, (a.y + b4.y) * inv,
                            (a.z + b4.z) * inv, (a.w + b4.w) * inv);
        }
        T[dc + 0][row] = v.x; T[dc + 1][row] = v.y;
        T[dc + 2][row] = v.z; T[dc + 3][row] = v.w;
    }
    __syncthreads();
    const int d = tid >> 2, ch = (tid & 3) * 16;
    const int lbase = lt * 64 + ch;
    if (lbase + 15 < L_) {
        float* dst = &out[((size_t)(bh * HD + d)) * L_ + lbase];
#pragma unroll
        for (int i = 0; i < 4; i++)
            *(float4*)&dst[4 * i] = *(const float4*)&T[d][ch + 4 * i];
    }
}

extern "C" void kernel_launch(void* const* d_in, const int* in_sizes, int n_in,
                              void* d_out, int out_size, void* d_ws, size_t ws_size,
                              hipStream_t stream) {
    const float* x   = (const float*)d_in[0];
    const float* rpe = (const float*)d_in[1];
    const float* Wq  = (const float*)d_in[2];
    const float* bq  = (const float*)d_in[3];
    const float* Wkv = (const float*)d_in[4];
    const float* bkv = (const float*)d_in[5];
    const float* Wl  = (const float*)d_in[6];
    const float* bl  = (const float*)d_in[7];
    float* out = (float*)d_out;

    unsigned short* wsu  = (unsigned short*)d_ws;
    unsigned short* x16  = wsu;                 // 4,096,000
    unsigned short* kv16 = wsu + 4096000;       // 4,096,000
    unsigned short* Wq16 = wsu + 8192000;       //   262,144
    unsigned short* Wkv16= wsu + 8454144;       //   524,288
    unsigned short* Q16  = wsu + 8978432;       // 4,194,304  [bh][2048][64]
    unsigned short* K16  = wsu + 13172736;      // 4,194,304  [bh][2048][64]
    unsigned short* V16  = wsu + 17367040;      // 4,194,304  [bh][64][2048]
    float* po   = (float*)(wsu + 21561344);     // 8,192,000 fp32 [2][32][2000][64]
    float* lsum = po + 8192000;                 //   131,072 fp32 [2][32][2048]

    conv_kernel<<<(B_ * L_ * C_ / 4 + 255) / 256, 256, 0, stream>>>(x, Wl, bl, kv16, x16);
    cvt_kernel<<<(786432 / 4 + 255) / 256, 256, 0, stream>>>(Wq, Wkv, Wq16, Wkv16);
    proj_mfma<<<dim3(125, 8), 256, 0, stream>>>(x16, Wq16, bq, Q16, nullptr, 0);
    proj_mfma<<<dim3(125, 16), 256, 0, stream>>>(kv16, Wkv16, bkv, K16, V16, 1);
    attn_mfma<<<512, 256, 0, stream>>>(Q16, K16, V16, rpe, po, lsum);
    merge_kernel<<<1024, 256, 0, stream>>>(po, lsum, out);
}

// Round 7
// 557.712 us; speedup vs baseline: 1.2768x; 1.0696x over previous
//
#include <hip/hip_runtime.h>

#define B_ 4
#define L_ 2000
#define LP 2048       // padded length for Q/K/V buffers
#define C_ 512
#define H_ 8
#define HD 64
#define CHUNK_ 1000

typedef __attribute__((ext_vector_type(8))) short bf16x8;
typedef __attribute__((ext_vector_type(4))) float f32x4;

__device__ inline unsigned short f2bf(float f) {
    union { float f; unsigned int u; } v; v.f = f;
    unsigned int r = v.u + 0x7fffu + ((v.u >> 16) & 1u);
    return (unsigned short)(r >> 16);
}

// -------------------------------------------------------------------------
// conv (depthwise k=3, zero pad at 1000-chunk boundaries) + residual + bias,
// bf16 out; also emits x cast to bf16. Vectorized x4 over channels.
// -------------------------------------------------------------------------
__global__ void conv_kernel(const float* __restrict__ x, const float* __restrict__ Wl,
                            const float* __restrict__ bl,
                            unsigned short* __restrict__ kv16,
                            unsigned short* __restrict__ x16) {
    int i4 = blockIdx.x * 256 + threadIdx.x;
    if (i4 >= B_ * L_ * C_ / 4) return;
    int idx = i4 * 4;
    int c = idx & (C_ - 1);
    int l = (idx >> 9) % L_;
    int p = l % CHUNK_;
    float4 xc = *(const float4*)&x[idx];
    float4 lf = (p > 0)          ? *(const float4*)&x[idx - C_] : make_float4(0, 0, 0, 0);
    float4 rt = (p < CHUNK_ - 1) ? *(const float4*)&x[idx + C_] : make_float4(0, 0, 0, 0);
    float y[4];
    const float* xcp = &xc.x; const float* lfp = &lf.x; const float* rtp = &rt.x;
#pragma unroll
    for (int j = 0; j < 4; j++) {
        y[j] = xcp[j] + bl[c + j] + Wl[(c + j) * 3 + 0] * lfp[j]
             + Wl[(c + j) * 3 + 1] * xcp[j] + Wl[(c + j) * 3 + 2] * rtp[j];
    }
    ushort4 kv = make_ushort4(f2bf(y[0]), f2bf(y[1]), f2bf(y[2]), f2bf(y[3]));
    ushort4 xo = make_ushort4(f2bf(xcp[0]), f2bf(xcp[1]), f2bf(xcp[2]), f2bf(xcp[3]));
    *(ushort4*)&kv16[idx] = kv;
    *(ushort4*)&x16[idx]  = xo;
}

// Both weight tensors cast in one launch (x4 vectorized).
__global__ void cvt_kernel(const float* __restrict__ Wq, const float* __restrict__ Wkv,
                           unsigned short* __restrict__ Wq16,
                           unsigned short* __restrict__ Wkv16) {
    int i4 = blockIdx.x * 256 + threadIdx.x;
    int idx = i4 * 4;
    const float* src; unsigned short* dst; int off;
    if (idx < 262144) { src = Wq; dst = Wq16; off = idx; }
    else if (idx < 786432) { src = Wkv; dst = Wkv16; off = idx - 262144; }
    else return;
    float4 v = *(const float4*)&src[off];
    *(ushort4*)&dst[off] = make_ushort4(f2bf(v.x), f2bf(v.y), f2bf(v.z), f2bf(v.w));
}

// -------------------------------------------------------------------------
// Projection GEMM via MFMA, LDS-staged coalesced epilogue.
// A:[8000][512] bf16, W:[N][512] bf16. Block: 4 waves, 64m x 64n tile.
// mode 0: Q -> [bh][2048][64]. mode 1: by<8 -> K [bh][2048][64];
//         by>=8 -> V transposed [bh][64][2048] (LDS transpose, row stores).
// -------------------------------------------------------------------------
__global__ __launch_bounds__(256) void proj_mfma(
    const unsigned short* __restrict__ A, const unsigned short* __restrict__ W,
    const float* __restrict__ bias,
    unsigned short* __restrict__ o0, unsigned short* __restrict__ o1, int mode) {
    __shared__ __align__(16) unsigned short tile[64][72];
    const int tid = threadIdx.x;
    const int lane = tid & 63;
    const int wave = tid >> 6;
    const int c = lane & 15;
    const int quad = lane >> 4;
    const int mrow = blockIdx.x * 64 + wave * 16 + c;
    const int n0 = blockIdx.y * 64;
    f32x4 acc[4] = {{0,0,0,0},{0,0,0,0},{0,0,0,0},{0,0,0,0}};
    const unsigned short* Ap = A + (size_t)mrow * C_ + quad * 8;
#pragma unroll 4
    for (int k0 = 0; k0 < C_; k0 += 32) {
        bf16x8 a = *(const bf16x8*)(Ap + k0);
#pragma unroll
        for (int t = 0; t < 4; t++) {
            bf16x8 wv = *(const bf16x8*)&W[(size_t)(n0 + 16 * t + c) * C_ + k0 + quad * 8];
            acc[t] = __builtin_amdgcn_mfma_f32_16x16x32_bf16(a, wv, acc[t], 0, 0, 0);
        }
    }
    const bool vpath = (mode == 1 && n0 >= C_);
    const int lm = wave * 16 + quad * 4;
#pragma unroll
    for (int t = 0; t < 4; t++) {
        float bv = bias[n0 + 16 * t + c];
#pragma unroll
        for (int r = 0; r < 4; r++) {
            unsigned short val = f2bf(acc[t][r] + bv);
            if (!vpath) tile[lm + r][16 * t + c] = val;   // [m][n]
            else        tile[16 * t + c][lm + r] = val;   // [n][m] transpose
        }
    }
    __syncthreads();
    if (!vpath) {
        int lr = tid >> 2, chunk = (tid & 3) * 16;
        int m = blockIdx.x * 64 + lr;
        int b = m / L_, l = m % L_;
        int nn = (n0 + chunk) & (C_ - 1);
        int h = nn >> 6, d0 = nn & 63;
        unsigned short* dst = &o0[(((size_t)(b * H_ + h) * LP) + l) * HD + d0];
        *(uint4*)dst       = *(const uint4*)&tile[lr][chunk];
        *(uint4*)(dst + 8) = *(const uint4*)&tile[lr][chunk + 8];
    } else {
        int dr = tid >> 2, chunk = (tid & 3) * 16;
        int nn = (n0 - C_) + dr;
        int h = nn >> 6, d = nn & 63;
        int mbase = blockIdx.x * 64 + chunk;
        int b0 = mbase / L_, b1 = (mbase + 15) / L_;
        if (b0 == b1) {
            int l = mbase % L_;
            unsigned short* dst = &o1[(((size_t)(b0 * H_ + h) * HD) + d) * LP + l];
            *(uint4*)dst       = *(const uint4*)&tile[dr][chunk];
            *(uint4*)(dst + 8) = *(const uint4*)&tile[dr][chunk + 8];
        } else {
            for (int i = 0; i < 16; i++) {
                int m = mbase + i;
                int b = m / L_, l = m % L_;
                o1[(((size_t)(b * H_ + h) * HD) + d) * LP + l] = tile[dr][chunk + i];
            }
        }
    }
}

// -------------------------------------------------------------------------
// Flash attention, bf16 MFMA. ONE BLOCK = ALL 4 BATCHES of (h, 64-row tile,
// K-half). LDS-staged K/V, transposed-S MFMA (lane owns one q-row, 4+4
// consecutive k-cols), 2-deep rpe double-buffer.
// ROUND-6 (resubmitted after infra failure): round-5 still showed 467MB
// WRITE_SIZE (vs 33MB legit) with clean FETCH -- signature of scratch
// traffic (spill stores dirty L2 -> HBM writeback; reloads hit L2).
// Cause: `const float* rpt = &rpl[t].x` ADDRESS-TAKES the register float4
// array -> forced to scratch, stored+reloaded every iteration on the exp2
// critical path. Fix: by-value float4 access with named .x/.y/.z/.w
// components. No other changes.
// -------------------------------------------------------------------------
__global__ __launch_bounds__(256, 2) void attn_mfma(
    const unsigned short* __restrict__ Q, const unsigned short* __restrict__ K,
    const unsigned short* __restrict__ Vt, const float* __restrict__ rpe,
    float* __restrict__ po, float* __restrict__ lsum) {
    __shared__ __align__(16) unsigned short Ks[4][32][72];   // [b][s-col][k=64+pad]
    __shared__ __align__(16) unsigned short Vs[4][64][40];   // [b][d][l=32+pad]
    __shared__ __align__(16) unsigned short Ps[4][2][16][40];// [wave][b&1][qrow][kcol]
    const int tid = threadIdx.x;
    const int lane = tid & 63;
    const int wave = tid >> 6;
    const int c = lane & 15;
    const int quad = lane >> 4;
    const int bid = blockIdx.x;
    const int ks = bid & 1;
    const int h  = (bid >> 1) & 7;
    const int rt = bid >> 4;
    const int r0w = rt * 64 + wave * 16;
    const int rg0 = r0w + quad * 4;        // o_acc row base (epilogue)
    // per-lane rpe row pointer (row = r0w + c, clamped; hoisted 64-bit math)
    const int rgc = min(r0w + c, L_ - 1);
    const float* rrow = rpe + (size_t)h * L_ * L_ + (size_t)rgc * L_;

    // staging coords: K tile [32 rows][64 k] (128B rows), V tile [64 d][32 l]
    const int krow = tid >> 3, kcol = (tid & 7) * 8;
    const int vrow = tid >> 2, vcol = (tid & 3) * 8;

    bf16x8 qf0[4], qf1[4];
    const unsigned short* Kp[4];
    const unsigned short* Vp[4];
    const int kt0 = ks * 32, kt1 = kt0 + 32;
#pragma unroll
    for (int b = 0; b < 4; b++) {
        const unsigned short* Qb = Q + (size_t)(b * H_ + h) * LP * HD;
        qf0[b] = *(const bf16x8*)&Qb[(size_t)(r0w + c) * HD + quad * 8];
        qf1[b] = *(const bf16x8*)&Qb[(size_t)(r0w + c) * HD + 32 + quad * 8];
        Kp[b] = K  + (size_t)(b * H_ + h) * LP * HD + (size_t)krow * HD + kcol
                  + (size_t)(kt0 * 32) * HD;
        Vp[b] = Vt + (size_t)(b * H_ + h) * HD * LP + (size_t)vrow * LP + vcol
                  + kt0 * 32;
    }

    float l_i[4] = {0.f, 0.f, 0.f, 0.f};
    f32x4 o_acc[4][4];
#pragma unroll
    for (int b = 0; b < 4; b++)
#pragma unroll
        for (int t = 0; t < 4; t++) o_acc[b][t] = (f32x4){0.f, 0.f, 0.f, 0.f};

    // ---- rpe loader: cols kt*32 + 16t + quad*4 .. +3 at fixed row.
    //      By-value float4, no address-taking (scratch-spill fix). ----
    const float LOG2E = 1.44269504f;
#define LOAD_RPE(d0, d1, KT)                                                 \
    {                                                                        \
        int cb0 = (KT) * 32 + quad * 4;                                      \
        int cb1 = cb0 + 16;                                                  \
        float4 raw0 = *(const float4*)&rrow[min(cb0, L_ - 4)];               \
        float4 raw1 = *(const float4*)&rrow[min(cb1, L_ - 4)];               \
        d0 = (cb0 <= L_ - 4) ? make_float4(raw0.x * LOG2E, raw0.y * LOG2E,   \
                                           raw0.z * LOG2E, raw0.w * LOG2E)  \
                             : make_float4(-1e30f, -1e30f, -1e30f, -1e30f);  \
        d1 = (cb1 <= L_ - 4) ? make_float4(raw1.x * LOG2E, raw1.y * LOG2E,   \
                                           raw1.z * LOG2E, raw1.w * LOG2E)  \
                             : make_float4(-1e30f, -1e30f, -1e30f, -1e30f);  \
    }

    // ---- prologue: first K/V tiles + first rpe tile ----
    uint4 kpre[4], vpre[4];
    float4 rpl0, rpl1;
#pragma unroll
    for (int b = 0; b < 4; b++) {
        kpre[b] = *(const uint4*)Kp[b];
        vpre[b] = *(const uint4*)Vp[b];
    }
    LOAD_RPE(rpl0, rpl1, kt0)

    for (int kt = kt0; kt < kt1; kt++) {
        __syncthreads();   // all waves done with previous tiles
#pragma unroll
        for (int b = 0; b < 4; b++) {
            *(uint4*)&Ks[b][krow][kcol] = kpre[b];
            *(uint4*)&Vs[b][vrow][vcol] = vpre[b];
        }
        __syncthreads();   // tiles visible

        // prefetch next K/V tiles + next rpe (consumed next iteration)
        float4 rpn0, rpn1;
        if (kt + 1 < kt1) {
#pragma unroll
            for (int b = 0; b < 4; b++) {
                Kp[b] += 32 * HD;
                Vp[b] += 32;
                kpre[b] = *(const uint4*)Kp[b];
                vpre[b] = *(const uint4*)Vp[b];
            }
            LOAD_RPE(rpn0, rpn1, kt + 1)
        }

        // ---- 4 per-batch chains ----
#pragma unroll
        for (int b = 0; b < 4; b++) {
            // S^T = K Q^T : lane holds logits for qrow=r0w+c,
            // kcols kt*32 + 16t + quad*4 + r
            f32x4 s0, s1;
            {
                bf16x8 k0f = *(const bf16x8*)&Ks[b][c][quad * 8];
                bf16x8 k1f = *(const bf16x8*)&Ks[b][c][32 + quad * 8];
                f32x4 z = {0.f, 0.f, 0.f, 0.f};
                z = __builtin_amdgcn_mfma_f32_16x16x32_bf16(k0f, qf0[b], z, 0, 0, 0);
                s0 = __builtin_amdgcn_mfma_f32_16x16x32_bf16(k1f, qf1[b], z, 0, 0, 0);
            }
            {
                bf16x8 k0f = *(const bf16x8*)&Ks[b][16 + c][quad * 8];
                bf16x8 k1f = *(const bf16x8*)&Ks[b][16 + c][32 + quad * 8];
                f32x4 z = {0.f, 0.f, 0.f, 0.f};
                z = __builtin_amdgcn_mfma_f32_16x16x32_bf16(k0f, qf0[b], z, 0, 0, 0);
                s1 = __builtin_amdgcn_mfma_f32_16x16x32_bf16(k1f, qf1[b], z, 0, 0, 0);
            }
            // p = exp2(s*scale*log2e + rpe*log2e); P^T -> Ps (packed b64)
            float psum;
            {
                float p0 = exp2f(fmaf(s0[0], 0.18033688f, rpl0.x));
                float p1 = exp2f(fmaf(s0[1], 0.18033688f, rpl0.y));
                float p2 = exp2f(fmaf(s0[2], 0.18033688f, rpl0.z));
                float p3 = exp2f(fmaf(s0[3], 0.18033688f, rpl0.w));
                psum = (p0 + p1) + (p2 + p3);
                *(ushort4*)&Ps[wave][b & 1][c][quad * 4] =
                    make_ushort4(f2bf(p0), f2bf(p1), f2bf(p2), f2bf(p3));
            }
            {
                float p0 = exp2f(fmaf(s1[0], 0.18033688f, rpl1.x));
                float p1 = exp2f(fmaf(s1[1], 0.18033688f, rpl1.y));
                float p2 = exp2f(fmaf(s1[2], 0.18033688f, rpl1.z));
                float p3 = exp2f(fmaf(s1[3], 0.18033688f, rpl1.w));
                psum += (p0 + p1) + (p2 + p3);
                *(ushort4*)&Ps[wave][b & 1][c][16 + quad * 4] =
                    make_ushort4(f2bf(p0), f2bf(p1), f2bf(p2), f2bf(p3));
            }
            l_i[b] += psum;
            // O += P V : K-dim 32, one MFMA per d-tile
            bf16x8 pa = *(const bf16x8*)&Ps[wave][b & 1][c][quad * 8];
#pragma unroll
            for (int t = 0; t < 4; t++) {
                bf16x8 v0 = *(const bf16x8*)&Vs[b][16 * t + c][quad * 8];
                o_acc[b][t] = __builtin_amdgcn_mfma_f32_16x16x32_bf16(pa, v0, o_acc[b][t], 0, 0, 0);
            }
        }
        if (kt + 1 < kt1) { rpl0 = rpn0; rpl1 = rpn1; }
    }

    // ---- epilogue: reduce l over quads; store raw partials ----
#pragma unroll
    for (int b = 0; b < 4; b++) {
        float v = l_i[b];
        v += __shfl_xor(v, 16);
        v += __shfl_xor(v, 32);
        float* pob = po + (size_t)(ks * 32 + b * H_ + h) * L_ * HD;
#pragma unroll
        for (int t = 0; t < 4; t++) {
            int d = 16 * t + c;
#pragma unroll
            for (int r = 0; r < 4; r++) {
                int l = rg0 + r;
                if (l < L_) pob[(size_t)l * HD + d] = o_acc[b][t][r];
            }
        }
        if (lane < 16) {
            float* lb = lsum + (size_t)(ks * 32 + b * H_ + h) * LP;
            lb[r0w + lane] = v;
        }
    }
#undef LOAD_RPE
}

// -------------------------------------------------------------------------
// Merge: out[bh][d][l] = (po0+po1)[bh][l][d] / (l0+l1)[bh][l], LDS transpose.
// -------------------------------------------------------------------------
__global__ __launch_bounds__(256) void merge_kernel(
    const float* __restrict__ po, const float* __restrict__ lsum,
    float* __restrict__ out) {
    __shared__ __align__(16) float T[64][68];
    const int tid = threadIdx.x;
    const int bh = blockIdx.x >> 5;
    const int lt = blockIdx.x & 31;
    const float* p0 = po + (size_t)bh * L_ * HD;
    const float* p1 = p0 + (size_t)32 * L_ * HD;
    const float* ls0 = lsum + (size_t)bh * LP;
    const float* ls1 = ls0 + (size_t)32 * LP;
#pragma unroll
    for (int it = 0; it < 4; it++) {
        int idx = it * 256 + tid;
        int row = idx >> 4;
        int dc = (idx & 15) * 4;
        int l = lt * 64 + row;
        float4 v = make_float4(0.f, 0.f, 0.f, 0.f);
        if (l < L_) {
            float4 a  = *(const float4*)&p0[(size_t)l * HD + dc];
            float4 b4 = *(const float4*)&p1[(size_t)l * HD + dc];
            float inv = 1.f / (ls0[l] + ls1[l]);
            v = make_float4((a.x + b4.x) * inv, (a.y + b4.y) * inv,
                            (a.z + b4.z) * inv, (a.w + b4.w) * inv);
        }
        T[dc + 0][row] = v.x; T[dc + 1][row] = v.y;
        T[dc + 2][row] = v.z; T[dc + 3][row] = v.w;
    }
    __syncthreads();
    const int d = tid >> 2, ch = (tid & 3) * 16;
    const int lbase = lt * 64 + ch;
    if (lbase + 15 < L_) {
        float* dst = &out[((size_t)(bh * HD + d)) * L_ + lbase];
#pragma unroll
        for (int i = 0; i < 4; i++)
            *(float4*)&dst[4 * i] = *(const float4*)&T[d][ch + 4 * i];
    }
}

extern "C" void kernel_launch(void* const* d_in, const int* in_sizes, int n_in,
                              void* d_out, int out_size, void* d_ws, size_t ws_size,
                              hipStream_t stream) {
    const float* x   = (const float*)d_in[0];
    const float* rpe = (const float*)d_in[1];
    const float* Wq  = (const float*)d_in[2];
    const float* bq  = (const float*)d_in[3];
    const float* Wkv = (const float*)d_in[4];
    const float* bkv = (const float*)d_in[5];
    const float* Wl  = (const float*)d_in[6];
    const float* bl  = (const float*)d_in[7];
    float* out = (float*)d_out;

    unsigned short* wsu  = (unsigned short*)d_ws;
    unsigned short* x16  = wsu;                 // 4,096,000
    unsigned short* kv16 = wsu + 4096000;       // 4,096,000
    unsigned short* Wq16 = wsu + 8192000;       //   262,144
    unsigned short* Wkv16= wsu + 8454144;       //   524,288
    unsigned short* Q16  = wsu + 8978432;       // 4,194,304  [bh][2048][64]
    unsigned short* K16  = wsu + 13172736;      // 4,194,304  [bh][2048][64]
    unsigned short* V16  = wsu + 17367040;      // 4,194,304  [bh][64][2048]
    float* po   = (float*)(wsu + 21561344);     // 8,192,000 fp32 [2][32][2000][64]
    float* lsum = po + 8192000;                 //   131,072 fp32 [2][32][2048]

    conv_kernel<<<(B_ * L_ * C_ / 4 + 255) / 256, 256, 0, stream>>>(x, Wl, bl, kv16, x16);
    cvt_kernel<<<(786432 / 4 + 255) / 256, 256, 0, stream>>>(Wq, Wkv, Wq16, Wkv16);
    proj_mfma<<<dim3(125, 8), 256, 0, stream>>>(x16, Wq16, bq, Q16, nullptr, 0);
    proj_mfma<<<dim3(125, 16), 256, 0, stream>>>(kv16, Wkv16, bkv, K16, V16, 1);
    attn_mfma<<<512, 256, 0, stream>>>(Q16, K16, V16, rpe, po, lsum);
    merge_kernel<<<1024, 256, 0, stream>>>(po, lsum, out);
}

// Round 8
// 414.423 us; speedup vs baseline: 1.7183x; 1.3458x over previous
//
#include <hip/hip_runtime.h>

#define B_ 4
#define L_ 2000
#define LP 2048       // padded length for Q/K/V buffers
#define C_ 512
#define H_ 8
#define HD 64
#define CHUNK_ 1000

typedef __attribute__((ext_vector_type(8))) short bf16x8;
typedef __attribute__((ext_vector_type(4))) float f32x4;

__device__ inline unsigned short f2bf(float f) {
    union { float f; unsigned int u; } v; v.f = f;
    unsigned int r = v.u + 0x7fffu + ((v.u >> 16) & 1u);
    return (unsigned short)(r >> 16);
}

// -------------------------------------------------------------------------
// conv (depthwise k=3, zero pad at 1000-chunk boundaries) + residual + bias,
// bf16 out; also emits x cast to bf16. Vectorized x4 over channels.
// -------------------------------------------------------------------------
__global__ void conv_kernel(const float* __restrict__ x, const float* __restrict__ Wl,
                            const float* __restrict__ bl,
                            unsigned short* __restrict__ kv16,
                            unsigned short* __restrict__ x16) {
    int i4 = blockIdx.x * 256 + threadIdx.x;
    if (i4 >= B_ * L_ * C_ / 4) return;
    int idx = i4 * 4;
    int c = idx & (C_ - 1);
    int l = (idx >> 9) % L_;
    int p = l % CHUNK_;
    float4 xc = *(const float4*)&x[idx];
    float4 lf = (p > 0)          ? *(const float4*)&x[idx - C_] : make_float4(0, 0, 0, 0);
    float4 rt = (p < CHUNK_ - 1) ? *(const float4*)&x[idx + C_] : make_float4(0, 0, 0, 0);
    float y[4];
    const float* xcp = &xc.x; const float* lfp = &lf.x; const float* rtp = &rt.x;
#pragma unroll
    for (int j = 0; j < 4; j++) {
        y[j] = xcp[j] + bl[c + j] + Wl[(c + j) * 3 + 0] * lfp[j]
             + Wl[(c + j) * 3 + 1] * xcp[j] + Wl[(c + j) * 3 + 2] * rtp[j];
    }
    ushort4 kv = make_ushort4(f2bf(y[0]), f2bf(y[1]), f2bf(y[2]), f2bf(y[3]));
    ushort4 xo = make_ushort4(f2bf(xcp[0]), f2bf(xcp[1]), f2bf(xcp[2]), f2bf(xcp[3]));
    *(ushort4*)&kv16[idx] = kv;
    *(ushort4*)&x16[idx]  = xo;
}

// Both weight tensors cast in one launch (x4 vectorized).
__global__ void cvt_kernel(const float* __restrict__ Wq, const float* __restrict__ Wkv,
                           unsigned short* __restrict__ Wq16,
                           unsigned short* __restrict__ Wkv16) {
    int i4 = blockIdx.x * 256 + threadIdx.x;
    int idx = i4 * 4;
    const float* src; unsigned short* dst; int off;
    if (idx < 262144) { src = Wq; dst = Wq16; off = idx; }
    else if (idx < 786432) { src = Wkv; dst = Wkv16; off = idx - 262144; }
    else return;
    float4 v = *(const float4*)&src[off];
    *(ushort4*)&dst[off] = make_ushort4(f2bf(v.x), f2bf(v.y), f2bf(v.z), f2bf(v.w));
}

// -------------------------------------------------------------------------
// Projection GEMM via MFMA, LDS-staged coalesced epilogue.
// A:[8000][512] bf16, W:[N][512] bf16. Block: 4 waves, 64m x 64n tile.
// mode 0: Q -> [bh][2048][64]. mode 1: by<8 -> K [bh][2048][64];
//         by>=8 -> V transposed [bh][64][2048] (LDS transpose, row stores).
// -------------------------------------------------------------------------
__global__ __launch_bounds__(256) void proj_mfma(
    const unsigned short* __restrict__ A, const unsigned short* __restrict__ W,
    const float* __restrict__ bias,
    unsigned short* __restrict__ o0, unsigned short* __restrict__ o1, int mode) {
    __shared__ __align__(16) unsigned short tile[64][72];
    const int tid = threadIdx.x;
    const int lane = tid & 63;
    const int wave = tid >> 6;
    const int c = lane & 15;
    const int quad = lane >> 4;
    const int mrow = blockIdx.x * 64 + wave * 16 + c;
    const int n0 = blockIdx.y * 64;
    f32x4 acc[4] = {{0,0,0,0},{0,0,0,0},{0,0,0,0},{0,0,0,0}};
    const unsigned short* Ap = A + (size_t)mrow * C_ + quad * 8;
#pragma unroll 4
    for (int k0 = 0; k0 < C_; k0 += 32) {
        bf16x8 a = *(const bf16x8*)(Ap + k0);
#pragma unroll
        for (int t = 0; t < 4; t++) {
            bf16x8 wv = *(const bf16x8*)&W[(size_t)(n0 + 16 * t + c) * C_ + k0 + quad * 8];
            acc[t] = __builtin_amdgcn_mfma_f32_16x16x32_bf16(a, wv, acc[t], 0, 0, 0);
        }
    }
    const bool vpath = (mode == 1 && n0 >= C_);
    const int lm = wave * 16 + quad * 4;
#pragma unroll
    for (int t = 0; t < 4; t++) {
        float bv = bias[n0 + 16 * t + c];
#pragma unroll
        for (int r = 0; r < 4; r++) {
            unsigned short val = f2bf(acc[t][r] + bv);
            if (!vpath) tile[lm + r][16 * t + c] = val;   // [m][n]
            else        tile[16 * t + c][lm + r] = val;   // [n][m] transpose
        }
    }
    __syncthreads();
    if (!vpath) {
        int lr = tid >> 2, chunk = (tid & 3) * 16;
        int m = blockIdx.x * 64 + lr;
        int b = m / L_, l = m % L_;
        int nn = (n0 + chunk) & (C_ - 1);
        int h = nn >> 6, d0 = nn & 63;
        unsigned short* dst = &o0[(((size_t)(b * H_ + h) * LP) + l) * HD + d0];
        *(uint4*)dst       = *(const uint4*)&tile[lr][chunk];
        *(uint4*)(dst + 8) = *(const uint4*)&tile[lr][chunk + 8];
    } else {
        int dr = tid >> 2, chunk = (tid & 3) * 16;
        int nn = (n0 - C_) + dr;
        int h = nn >> 6, d = nn & 63;
        int mbase = blockIdx.x * 64 + chunk;
        int b0 = mbase / L_, b1 = (mbase + 15) / L_;
        if (b0 == b1) {
            int l = mbase % L_;
            unsigned short* dst = &o1[(((size_t)(b0 * H_ + h) * HD) + d) * LP + l];
            *(uint4*)dst       = *(const uint4*)&tile[dr][chunk];
            *(uint4*)(dst + 8) = *(const uint4*)&tile[dr][chunk + 8];
        } else {
            for (int i = 0; i < 16; i++) {
                int m = mbase + i;
                int b = m / L_, l = m % L_;
                o1[(((size_t)(b * H_ + h) * HD) + d) * LP + l] = tile[dr][chunk + i];
            }
        }
    }
}

// -------------------------------------------------------------------------
// Flash attention, bf16 MFMA. ONE BLOCK = ALL 4 BATCHES of (h, 64-row tile,
// K-half). LDS-staged K/V, transposed-S MFMA (lane owns one q-row, 4+4
// consecutive k-cols), 2-deep rpe double-buffer.
// ROUND-8: WRITE_SIZE stayed at 469MB after the rpe by-value fix -> the
// remaining ~437MB of scratch traffic is the MUTABLE POINTER ARRAYS
// (Kp[4]/Vp[4], bumped every kt iteration) + uint4 kpre[4]/vpre[4]
// prefetch arrays -- aggregates mutated in a non-unrolled loop fail
// SROA and live in scratch (512blk x 256thr x 31it x ~115B = 470MB;
// VGPR=104 << ~170 live set corroborates). Fix: NAMED scalar prefetch
// regs (kpre0..3/vpre0..3), named const base pointers (Kb0..3/Vb0..3),
// uniform scalar offsets per iteration. Compute loop unchanged (its
// arrays are constant-indexed -- round-1-proven clean).
// -------------------------------------------------------------------------
__global__ __launch_bounds__(256, 2) void attn_mfma(
    const unsigned short* __restrict__ Q, const unsigned short* __restrict__ K,
    const unsigned short* __restrict__ Vt, const float* __restrict__ rpe,
    float* __restrict__ po, float* __restrict__ lsum) {
    __shared__ __align__(16) unsigned short Ks[4][32][72];   // [b][s-col][k=64+pad]
    __shared__ __align__(16) unsigned short Vs[4][64][40];   // [b][d][l=32+pad]
    __shared__ __align__(16) unsigned short Ps[4][2][16][40];// [wave][b&1][qrow][kcol]
    const int tid = threadIdx.x;
    const int lane = tid & 63;
    const int wave = tid >> 6;
    const int c = lane & 15;
    const int quad = lane >> 4;
    const int bid = blockIdx.x;
    const int ks = bid & 1;
    const int h  = (bid >> 1) & 7;
    const int rt = bid >> 4;
    const int r0w = rt * 64 + wave * 16;
    const int rg0 = r0w + quad * 4;        // o_acc row base (epilogue)
    // per-lane rpe row pointer (row = r0w + c, clamped; hoisted 64-bit math)
    const int rgc = min(r0w + c, L_ - 1);
    const float* rrow = rpe + (size_t)h * L_ * L_ + (size_t)rgc * L_;

    // staging coords: K tile [32 rows][64 k] (128B rows), V tile [64 d][32 l]
    const int krow = tid >> 3, kcol = (tid & 7) * 8;
    const int vrow = tid >> 2, vcol = (tid & 3) * 8;

    const int kt0 = ks * 32, kt1 = kt0 + 32;

    // named const staging base pointers (include kt0 offset)
    const unsigned short* Kb0 = K + (size_t)(0 * H_ + h) * LP * HD
        + (size_t)krow * HD + kcol + (size_t)(kt0 * 32) * HD;
    const unsigned short* Kb1 = Kb0 + (size_t)H_ * LP * HD;
    const unsigned short* Kb2 = Kb1 + (size_t)H_ * LP * HD;
    const unsigned short* Kb3 = Kb2 + (size_t)H_ * LP * HD;
    const unsigned short* Vb0 = Vt + (size_t)(0 * H_ + h) * HD * LP
        + (size_t)vrow * LP + vcol + kt0 * 32;
    const unsigned short* Vb1 = Vb0 + (size_t)H_ * HD * LP;
    const unsigned short* Vb2 = Vb1 + (size_t)H_ * HD * LP;
    const unsigned short* Vb3 = Vb2 + (size_t)H_ * HD * LP;

    bf16x8 qf0[4], qf1[4];
#pragma unroll
    for (int b = 0; b < 4; b++) {
        const unsigned short* Qb = Q + (size_t)(b * H_ + h) * LP * HD;
        qf0[b] = *(const bf16x8*)&Qb[(size_t)(r0w + c) * HD + quad * 8];
        qf1[b] = *(const bf16x8*)&Qb[(size_t)(r0w + c) * HD + 32 + quad * 8];
    }

    float l_i[4] = {0.f, 0.f, 0.f, 0.f};
    f32x4 o_acc[4][4];
#pragma unroll
    for (int b = 0; b < 4; b++)
#pragma unroll
        for (int t = 0; t < 4; t++) o_acc[b][t] = (f32x4){0.f, 0.f, 0.f, 0.f};

    // ---- rpe loader: cols kt*32 + 16t + quad*4 .. +3 at fixed row.
    //      By-value float4, no address-taking. ----
    const float LOG2E = 1.44269504f;
#define LOAD_RPE(d0, d1, KT)                                                 \
    {                                                                        \
        int cb0 = (KT) * 32 + quad * 4;                                      \
        int cb1 = cb0 + 16;                                                  \
        float4 raw0 = *(const float4*)&rrow[min(cb0, L_ - 4)];               \
        float4 raw1 = *(const float4*)&rrow[min(cb1, L_ - 4)];               \
        d0 = (cb0 <= L_ - 4) ? make_float4(raw0.x * LOG2E, raw0.y * LOG2E,   \
                                           raw0.z * LOG2E, raw0.w * LOG2E)  \
                             : make_float4(-1e30f, -1e30f, -1e30f, -1e30f);  \
        d1 = (cb1 <= L_ - 4) ? make_float4(raw1.x * LOG2E, raw1.y * LOG2E,   \
                                           raw1.z * LOG2E, raw1.w * LOG2E)  \
                             : make_float4(-1e30f, -1e30f, -1e30f, -1e30f);  \
    }

    // ---- prologue: first K/V tiles (named regs) + first rpe tile ----
    uint4 kpre0 = *(const uint4*)Kb0, kpre1 = *(const uint4*)Kb1;
    uint4 kpre2 = *(const uint4*)Kb2, kpre3 = *(const uint4*)Kb3;
    uint4 vpre0 = *(const uint4*)Vb0, vpre1 = *(const uint4*)Vb1;
    uint4 vpre2 = *(const uint4*)Vb2, vpre3 = *(const uint4*)Vb3;
    float4 rpl0, rpl1;
    LOAD_RPE(rpl0, rpl1, kt0)

    for (int kt = kt0; kt < kt1; kt++) {
        __syncthreads();   // all waves done with previous tiles
        *(uint4*)&Ks[0][krow][kcol] = kpre0;
        *(uint4*)&Ks[1][krow][kcol] = kpre1;
        *(uint4*)&Ks[2][krow][kcol] = kpre2;
        *(uint4*)&Ks[3][krow][kcol] = kpre3;
        *(uint4*)&Vs[0][vrow][vcol] = vpre0;
        *(uint4*)&Vs[1][vrow][vcol] = vpre1;
        *(uint4*)&Vs[2][vrow][vcol] = vpre2;
        *(uint4*)&Vs[3][vrow][vcol] = vpre3;
        __syncthreads();   // tiles visible

        // prefetch next K/V tiles (uniform scalar offsets) + next rpe
        float4 rpn0, rpn1;
        if (kt + 1 < kt1) {
            const size_t ko = (size_t)(kt + 1 - kt0) * 32 * HD;
            const int    vo = (kt + 1 - kt0) * 32;
            kpre0 = *(const uint4*)(Kb0 + ko);
            kpre1 = *(const uint4*)(Kb1 + ko);
            kpre2 = *(const uint4*)(Kb2 + ko);
            kpre3 = *(const uint4*)(Kb3 + ko);
            vpre0 = *(const uint4*)(Vb0 + vo);
            vpre1 = *(const uint4*)(Vb1 + vo);
            vpre2 = *(const uint4*)(Vb2 + vo);
            vpre3 = *(const uint4*)(Vb3 + vo);
            LOAD_RPE(rpn0, rpn1, kt + 1)
        }

        // ---- 4 per-batch chains (arrays here are constant-indexed) ----
#pragma unroll
        for (int b = 0; b < 4; b++) {
            // S^T = K Q^T : lane holds logits for qrow=r0w+c,
            // kcols kt*32 + 16t + quad*4 + r
            f32x4 s0, s1;
            {
                bf16x8 k0f = *(const bf16x8*)&Ks[b][c][quad * 8];
                bf16x8 k1f = *(const bf16x8*)&Ks[b][c][32 + quad * 8];
                f32x4 z = {0.f, 0.f, 0.f, 0.f};
                z = __builtin_amdgcn_mfma_f32_16x16x32_bf16(k0f, qf0[b], z, 0, 0, 0);
                s0 = __builtin_amdgcn_mfma_f32_16x16x32_bf16(k1f, qf1[b], z, 0, 0, 0);
            }
            {
                bf16x8 k0f = *(const bf16x8*)&Ks[b][16 + c][quad * 8];
                bf16x8 k1f = *(const bf16x8*)&Ks[b][16 + c][32 + quad * 8];
                f32x4 z = {0.f, 0.f, 0.f, 0.f};
                z = __builtin_amdgcn_mfma_f32_16x16x32_bf16(k0f, qf0[b], z, 0, 0, 0);
                s1 = __builtin_amdgcn_mfma_f32_16x16x32_bf16(k1f, qf1[b], z, 0, 0, 0);
            }
            // p = exp2(s*scale*log2e + rpe*log2e); P^T -> Ps (packed b64)
            float psum;
            {
                float p0 = exp2f(fmaf(s0[0], 0.18033688f, rpl0.x));
                float p1 = exp2f(fmaf(s0[1], 0.18033688f, rpl0.y));
                float p2 = exp2f(fmaf(s0[2], 0.18033688f, rpl0.z));
                float p3 = exp2f(fmaf(s0[3], 0.18033688f, rpl0.w));
                psum = (p0 + p1) + (p2 + p3);
                *(ushort4*)&Ps[wave][b & 1][c][quad * 4] =
                    make_ushort4(f2bf(p0), f2bf(p1), f2bf(p2), f2bf(p3));
            }
            {
                float p0 = exp2f(fmaf(s1[0], 0.18033688f, rpl1.x));
                float p1 = exp2f(fmaf(s1[1], 0.18033688f, rpl1.y));
                float p2 = exp2f(fmaf(s1[2], 0.18033688f, rpl1.z));
                float p3 = exp2f(fmaf(s1[3], 0.18033688f, rpl1.w));
                psum += (p0 + p1) + (p2 + p3);
                *(ushort4*)&Ps[wave][b & 1][c][16 + quad * 4] =
                    make_ushort4(f2bf(p0), f2bf(p1), f2bf(p2), f2bf(p3));
            }
            l_i[b] += psum;
            // O += P V : K-dim 32, one MFMA per d-tile
            bf16x8 pa = *(const bf16x8*)&Ps[wave][b & 1][c][quad * 8];
#pragma unroll
            for (int t = 0; t < 4; t++) {
                bf16x8 v0 = *(const bf16x8*)&Vs[b][16 * t + c][quad * 8];
                o_acc[b][t] = __builtin_amdgcn_mfma_f32_16x16x32_bf16(pa, v0, o_acc[b][t], 0, 0, 0);
            }
        }
        if (kt + 1 < kt1) { rpl0 = rpn0; rpl1 = rpn1; }
    }

    // ---- epilogue: reduce l over quads; store raw partials ----
#pragma unroll
    for (int b = 0; b < 4; b++) {
        float v = l_i[b];
        v += __shfl_xor(v, 16);
        v += __shfl_xor(v, 32);
        float* pob = po + (size_t)(ks * 32 + b * H_ + h) * L_ * HD;
#pragma unroll
        for (int t = 0; t < 4; t++) {
            int d = 16 * t + c;
#pragma unroll
            for (int r = 0; r < 4; r++) {
                int l = rg0 + r;
                if (l < L_) pob[(size_t)l * HD + d] = o_acc[b][t][r];
            }
        }
        if (lane < 16) {
            float* lb = lsum + (size_t)(ks * 32 + b * H_ + h) * LP;
            lb[r0w + lane] = v;
        }
    }
#undef LOAD_RPE
}

// -------------------------------------------------------------------------
// Merge: out[bh][d][l] = (po0+po1)[bh][l][d] / (l0+l1)[bh][l], LDS transpose.
// -------------------------------------------------------------------------
__global__ __launch_bounds__(256) void merge_kernel(
    const float* __restrict__ po, const float* __restrict__ lsum,
    float* __restrict__ out) {
    __shared__ __align__(16) float T[64][68];
    const int tid = threadIdx.x;
    const int bh = blockIdx.x >> 5;
    const int lt = blockIdx.x & 31;
    const float* p0 = po + (size_t)bh * L_ * HD;
    const float* p1 = p0 + (size_t)32 * L_ * HD;
    const float* ls0 = lsum + (size_t)bh * LP;
    const float* ls1 = ls0 + (size_t)32 * LP;
#pragma unroll
    for (int it = 0; it < 4; it++) {
        int idx = it * 256 + tid;
        int row = idx >> 4;
        int dc = (idx & 15) * 4;
        int l = lt * 64 + row;
        float4 v = make_float4(0.f, 0.f, 0.f, 0.f);
        if (l < L_) {
            float4 a  = *(const float4*)&p0[(size_t)l * HD + dc];
            float4 b4 = *(const float4*)&p1[(size_t)l * HD + dc];
            float inv = 1.f / (ls0[l] + ls1[l]);
            v = make_float4((a.x + b4.x) * inv, (a.y + b4.y) * inv,
                            (a.z + b4.z) * inv, (a.w + b4.w) * inv);
        }
        T[dc + 0][row] = v.x; T[dc + 1][row] = v.y;
        T[dc + 2][row] = v.z; T[dc + 3][row] = v.w;
    }
    __syncthreads();
    const int d = tid >> 2, ch = (tid & 3) * 16;
    const int lbase = lt * 64 + ch;
    if (lbase + 15 < L_) {
        float* dst = &out[((size_t)(bh * HD + d)) * L_ + lbase];
#pragma unroll
        for (int i = 0; i < 4; i++)
            *(float4*)&dst[4 * i] = *(const float4*)&T[d][ch + 4 * i];
    }
}

extern "C" void kernel_launch(void* const* d_in, const int* in_sizes, int n_in,
                              void* d_out, int out_size, void* d_ws, size_t ws_size,
                              hipStream_t stream) {
    const float* x   = (const float*)d_in[0];
    const float* rpe = (const float*)d_in[1];
    const float* Wq  = (const float*)d_in[2];
    const float* bq  = (const float*)d_in[3];
    const float* Wkv = (const float*)d_in[4];
    const float* bkv = (const float*)d_in[5];
    const float* Wl  = (const float*)d_in[6];
    const float* bl  = (const float*)d_in[7];
    float* out = (float*)d_out;

    unsigned short* wsu  = (unsigned short*)d_ws;
    unsigned short* x16  = wsu;                 // 4,096,000
    unsigned short* kv16 = wsu + 4096000;       // 4,096,000
    unsigned short* Wq16 = wsu + 8192000;       //   262,144
    unsigned short* Wkv16= wsu + 8454144;       //   524,288
    unsigned short* Q16  = wsu + 8978432;       // 4,194,304  [bh][2048][64]
    unsigned short* K16  = wsu + 13172736;      // 4,194,304  [bh][2048][64]
    unsigned short* V16  = wsu + 17367040;      // 4,194,304  [bh][64][2048]
    float* po   = (float*)(wsu + 21561344);     // 8,192,000 fp32 [2][32][2000][64]
    float* lsum = po + 8192000;                 //   131,072 fp32 [2][32][2048]

    conv_kernel<<<(B_ * L_ * C_ / 4 + 255) / 256, 256, 0, stream>>>(x, Wl, bl, kv16, x16);
    cvt_kernel<<<(786432 / 4 + 255) / 256, 256, 0, stream>>>(Wq, Wkv, Wq16, Wkv16);
    proj_mfma<<<dim3(125, 8), 256, 0, stream>>>(x16, Wq16, bq, Q16, nullptr, 0);
    proj_mfma<<<dim3(125, 16), 256, 0, stream>>>(kv16, Wkv16, bkv, K16, V16, 1);
    attn_mfma<<<512, 256, 0, stream>>>(Q16, K16, V16, rpe, po, lsum);
    merge_kernel<<<1024, 256, 0, stream>>>(po, lsum, out);
}

// Round 9
// 410.925 us; speedup vs baseline: 1.7329x; 1.0085x over previous
//
#include <hip/hip_runtime.h>

#define B_ 4
#define L_ 2000
#define LP 2048       // padded length for Q/K/V buffers
#define C_ 512
#define H_ 8
#define HD 64
#define CHUNK_ 1000

typedef __attribute__((ext_vector_type(8))) short bf16x8;
typedef __attribute__((ext_vector_type(4))) float f32x4;

__device__ inline unsigned short f2bf(float f) {
    union { float f; unsigned int u; } v; v.f = f;
    unsigned int r = v.u + 0x7fffu + ((v.u >> 16) & 1u);
    return (unsigned short)(r >> 16);
}

// -------------------------------------------------------------------------
// conv (depthwise k=3, zero pad at 1000-chunk boundaries) + residual + bias,
// bf16 out; also emits x cast to bf16. Vectorized x4 over channels.
// -------------------------------------------------------------------------
__global__ void conv_kernel(const float* __restrict__ x, const float* __restrict__ Wl,
                            const float* __restrict__ bl,
                            unsigned short* __restrict__ kv16,
                            unsigned short* __restrict__ x16) {
    int i4 = blockIdx.x * 256 + threadIdx.x;
    if (i4 >= B_ * L_ * C_ / 4) return;
    int idx = i4 * 4;
    int c = idx & (C_ - 1);
    int l = (idx >> 9) % L_;
    int p = l % CHUNK_;
    float4 xc = *(const float4*)&x[idx];
    float4 lf = (p > 0)          ? *(const float4*)&x[idx - C_] : make_float4(0, 0, 0, 0);
    float4 rt = (p < CHUNK_ - 1) ? *(const float4*)&x[idx + C_] : make_float4(0, 0, 0, 0);
    float y[4];
    const float* xcp = &xc.x; const float* lfp = &lf.x; const float* rtp = &rt.x;
#pragma unroll
    for (int j = 0; j < 4; j++) {
        y[j] = xcp[j] + bl[c + j] + Wl[(c + j) * 3 + 0] * lfp[j]
             + Wl[(c + j) * 3 + 1] * xcp[j] + Wl[(c + j) * 3 + 2] * rtp[j];
    }
    ushort4 kv = make_ushort4(f2bf(y[0]), f2bf(y[1]), f2bf(y[2]), f2bf(y[3]));
    ushort4 xo = make_ushort4(f2bf(xcp[0]), f2bf(xcp[1]), f2bf(xcp[2]), f2bf(xcp[3]));
    *(ushort4*)&kv16[idx] = kv;
    *(ushort4*)&x16[idx]  = xo;
}

// Both weight tensors cast in one launch (x4 vectorized).
__global__ void cvt_kernel(const float* __restrict__ Wq, const float* __restrict__ Wkv,
                           unsigned short* __restrict__ Wq16,
                           unsigned short* __restrict__ Wkv16) {
    int i4 = blockIdx.x * 256 + threadIdx.x;
    int idx = i4 * 4;
    const float* src; unsigned short* dst; int off;
    if (idx < 262144) { src = Wq; dst = Wq16; off = idx; }
    else if (idx < 786432) { src = Wkv; dst = Wkv16; off = idx - 262144; }
    else return;
    float4 v = *(const float4*)&src[off];
    *(ushort4*)&dst[off] = make_ushort4(f2bf(v.x), f2bf(v.y), f2bf(v.z), f2bf(v.w));
}

// -------------------------------------------------------------------------
// Projection GEMM via MFMA, LDS-staged coalesced epilogue.
// A:[8000][512] bf16, W:[N][512] bf16. Block: 4 waves, 64m x 64n tile.
// mode 0: Q -> [bh][2048][64]. mode 1: by<8 -> K [bh][2048][64];
//         by>=8 -> V transposed [bh][64][2048] (LDS transpose, row stores).
// -------------------------------------------------------------------------
__global__ __launch_bounds__(256) void proj_mfma(
    const unsigned short* __restrict__ A, const unsigned short* __restrict__ W,
    const float* __restrict__ bias,
    unsigned short* __restrict__ o0, unsigned short* __restrict__ o1, int mode) {
    __shared__ __align__(16) unsigned short tile[64][72];
    const int tid = threadIdx.x;
    const int lane = tid & 63;
    const int wave = tid >> 6;
    const int c = lane & 15;
    const int quad = lane >> 4;
    const int mrow = blockIdx.x * 64 + wave * 16 + c;
    const int n0 = blockIdx.y * 64;
    f32x4 acc[4] = {{0,0,0,0},{0,0,0,0},{0,0,0,0},{0,0,0,0}};
    const unsigned short* Ap = A + (size_t)mrow * C_ + quad * 8;
#pragma unroll 4
    for (int k0 = 0; k0 < C_; k0 += 32) {
        bf16x8 a = *(const bf16x8*)(Ap + k0);
#pragma unroll
        for (int t = 0; t < 4; t++) {
            bf16x8 wv = *(const bf16x8*)&W[(size_t)(n0 + 16 * t + c) * C_ + k0 + quad * 8];
            acc[t] = __builtin_amdgcn_mfma_f32_16x16x32_bf16(a, wv, acc[t], 0, 0, 0);
        }
    }
    const bool vpath = (mode == 1 && n0 >= C_);
    const int lm = wave * 16 + quad * 4;
#pragma unroll
    for (int t = 0; t < 4; t++) {
        float bv = bias[n0 + 16 * t + c];
#pragma unroll
        for (int r = 0; r < 4; r++) {
            unsigned short val = f2bf(acc[t][r] + bv);
            if (!vpath) tile[lm + r][16 * t + c] = val;   // [m][n]
            else        tile[16 * t + c][lm + r] = val;   // [n][m] transpose
        }
    }
    __syncthreads();
    if (!vpath) {
        int lr = tid >> 2, chunk = (tid & 3) * 16;
        int m = blockIdx.x * 64 + lr;
        int b = m / L_, l = m % L_;
        int nn = (n0 + chunk) & (C_ - 1);
        int h = nn >> 6, d0 = nn & 63;
        unsigned short* dst = &o0[(((size_t)(b * H_ + h) * LP) + l) * HD + d0];
        *(uint4*)dst       = *(const uint4*)&tile[lr][chunk];
        *(uint4*)(dst + 8) = *(const uint4*)&tile[lr][chunk + 8];
    } else {
        int dr = tid >> 2, chunk = (tid & 3) * 16;
        int nn = (n0 - C_) + dr;
        int h = nn >> 6, d = nn & 63;
        int mbase = blockIdx.x * 64 + chunk;
        int b0 = mbase / L_, b1 = (mbase + 15) / L_;
        if (b0 == b1) {
            int l = mbase % L_;
            unsigned short* dst = &o1[(((size_t)(b0 * H_ + h) * HD) + d) * LP + l];
            *(uint4*)dst       = *(const uint4*)&tile[dr][chunk];
            *(uint4*)(dst + 8) = *(const uint4*)&tile[dr][chunk + 8];
        } else {
            for (int i = 0; i < 16; i++) {
                int m = mbase + i;
                int b = m / L_, l = m % L_;
                o1[(((size_t)(b * H_ + h) * HD) + d) * LP + l] = tile[dr][chunk + i];
            }
        }
    }
}

// -------------------------------------------------------------------------
// Flash attention, bf16 MFMA. LDS-staged K/V, transposed-S MFMA (lane owns
// one q-row, 4+4 consecutive k-cols), 2-deep rpe double-buffer, NAMED
// scalar prefetch regs (round-8 scratch fix: no mutable arrays).
// ROUND-9: round 8 cleaned scratch (WRITE 469->32.5MB) and hit 134us, but
// counters show nothing saturated (HBM 11%, Mfma 11%, VALU 38%, Occ 20%)
// -> latency-bound at 2 blocks/CU. Split batch 4->2 per block: grid 1024
// = 4 blocks/CU = 4 waves/SIMD (launch_bounds(256,4); LDS halves to 30KB
// so 4 blocks fit). bp bit at bid bit 4 -> the two blocks sharing an rpe
// tile are 16 apart -> same XCD under 8-XCD round-robin -> rpe L2-shared.
// (Round 2's regression with this split was under direct-global K/V --
// TA-request-bound -- and the latent scratch bug; both fixed since.)
// po/lsum/merge layouts unchanged.
// -------------------------------------------------------------------------
__global__ __launch_bounds__(256, 4) void attn_mfma(
    const unsigned short* __restrict__ Q, const unsigned short* __restrict__ K,
    const unsigned short* __restrict__ Vt, const float* __restrict__ rpe,
    float* __restrict__ po, float* __restrict__ lsum) {
    __shared__ __align__(16) unsigned short Ks[2][32][72];   // [i][s-col][k=64+pad]
    __shared__ __align__(16) unsigned short Vs[2][64][40];   // [i][d][l=32+pad]
    __shared__ __align__(16) unsigned short Ps[4][2][16][40];// [wave][i][qrow][kcol]
    const int tid = threadIdx.x;
    const int lane = tid & 63;
    const int wave = tid >> 6;
    const int c = lane & 15;
    const int quad = lane >> 4;
    const int bid = blockIdx.x;
    const int ks = bid & 1;
    const int h  = (bid >> 1) & 7;
    const int bp = (bid >> 4) & 1;   // batch pair: handles b = 2*bp, 2*bp+1
    const int rt = bid >> 5;
    const int r0w = rt * 64 + wave * 16;
    const int rg0 = r0w + quad * 4;        // o_acc row base (epilogue)
    // per-lane rpe row pointer (row = r0w + c, clamped; hoisted 64-bit math)
    const int rgc = min(r0w + c, L_ - 1);
    const float* rrow = rpe + (size_t)h * L_ * L_ + (size_t)rgc * L_;

    // staging coords: K tile [32 rows][64 k] (128B rows), V tile [64 d][32 l]
    const int krow = tid >> 3, kcol = (tid & 7) * 8;
    const int vrow = tid >> 2, vcol = (tid & 3) * 8;

    const int kt0 = ks * 32, kt1 = kt0 + 32;

    // named const staging base pointers (include kt0 offset); batches 2bp,2bp+1
    const unsigned short* Kb0 = K + (size_t)((bp * 2) * H_ + h) * LP * HD
        + (size_t)krow * HD + kcol + (size_t)(kt0 * 32) * HD;
    const unsigned short* Kb1 = Kb0 + (size_t)H_ * LP * HD;
    const unsigned short* Vb0 = Vt + (size_t)((bp * 2) * H_ + h) * HD * LP
        + (size_t)vrow * LP + vcol + kt0 * 32;
    const unsigned short* Vb1 = Vb0 + (size_t)H_ * HD * LP;

    bf16x8 qf0[2], qf1[2];
#pragma unroll
    for (int b = 0; b < 2; b++) {
        const unsigned short* Qb = Q + (size_t)((bp * 2 + b) * H_ + h) * LP * HD;
        qf0[b] = *(const bf16x8*)&Qb[(size_t)(r0w + c) * HD + quad * 8];
        qf1[b] = *(const bf16x8*)&Qb[(size_t)(r0w + c) * HD + 32 + quad * 8];
    }

    float l_i[2] = {0.f, 0.f};
    f32x4 o_acc[2][4];
#pragma unroll
    for (int b = 0; b < 2; b++)
#pragma unroll
        for (int t = 0; t < 4; t++) o_acc[b][t] = (f32x4){0.f, 0.f, 0.f, 0.f};

    // ---- rpe loader: cols kt*32 + 16t + quad*4 .. +3 at fixed row.
    //      By-value float4, no address-taking. ----
    const float LOG2E = 1.44269504f;
#define LOAD_RPE(d0, d1, KT)                                                 \
    {                                                                        \
        int cb0 = (KT) * 32 + quad * 4;                                      \
        int cb1 = cb0 + 16;                                                  \
        float4 raw0 = *(const float4*)&rrow[min(cb0, L_ - 4)];               \
        float4 raw1 = *(const float4*)&rrow[min(cb1, L_ - 4)];               \
        d0 = (cb0 <= L_ - 4) ? make_float4(raw0.x * LOG2E, raw0.y * LOG2E,   \
                                           raw0.z * LOG2E, raw0.w * LOG2E)  \
                             : make_float4(-1e30f, -1e30f, -1e30f, -1e30f);  \
        d1 = (cb1 <= L_ - 4) ? make_float4(raw1.x * LOG2E, raw1.y * LOG2E,   \
                                           raw1.z * LOG2E, raw1.w * LOG2E)  \
                             : make_float4(-1e30f, -1e30f, -1e30f, -1e30f);  \
    }

    // ---- prologue: first K/V tiles (named regs) + first rpe tile ----
    uint4 kpre0 = *(const uint4*)Kb0, kpre1 = *(const uint4*)Kb1;
    uint4 vpre0 = *(const uint4*)Vb0, vpre1 = *(const uint4*)Vb1;
    float4 rpl0, rpl1;
    LOAD_RPE(rpl0, rpl1, kt0)

    for (int kt = kt0; kt < kt1; kt++) {
        __syncthreads();   // all waves done with previous tiles
        *(uint4*)&Ks[0][krow][kcol] = kpre0;
        *(uint4*)&Ks[1][krow][kcol] = kpre1;
        *(uint4*)&Vs[0][vrow][vcol] = vpre0;
        *(uint4*)&Vs[1][vrow][vcol] = vpre1;
        __syncthreads();   // tiles visible

        // prefetch next K/V tiles (uniform scalar offsets) + next rpe
        float4 rpn0, rpn1;
        if (kt + 1 < kt1) {
            const size_t ko = (size_t)(kt + 1 - kt0) * 32 * HD;
            const int    vo = (kt + 1 - kt0) * 32;
            kpre0 = *(const uint4*)(Kb0 + ko);
            kpre1 = *(const uint4*)(Kb1 + ko);
            vpre0 = *(const uint4*)(Vb0 + vo);
            vpre1 = *(const uint4*)(Vb1 + vo);
            LOAD_RPE(rpn0, rpn1, kt + 1)
        }

        // ---- 2 per-batch chains (arrays here are constant-indexed) ----
#pragma unroll
        for (int b = 0; b < 2; b++) {
            // S^T = K Q^T : lane holds logits for qrow=r0w+c,
            // kcols kt*32 + 16t + quad*4 + r
            f32x4 s0, s1;
            {
                bf16x8 k0f = *(const bf16x8*)&Ks[b][c][quad * 8];
                bf16x8 k1f = *(const bf16x8*)&Ks[b][c][32 + quad * 8];
                f32x4 z = {0.f, 0.f, 0.f, 0.f};
                z = __builtin_amdgcn_mfma_f32_16x16x32_bf16(k0f, qf0[b], z, 0, 0, 0);
                s0 = __builtin_amdgcn_mfma_f32_16x16x32_bf16(k1f, qf1[b], z, 0, 0, 0);
            }
            {
                bf16x8 k0f = *(const bf16x8*)&Ks[b][16 + c][quad * 8];
                bf16x8 k1f = *(const bf16x8*)&Ks[b][16 + c][32 + quad * 8];
                f32x4 z = {0.f, 0.f, 0.f, 0.f};
                z = __builtin_amdgcn_mfma_f32_16x16x32_bf16(k0f, qf0[b], z, 0, 0, 0);
                s1 = __builtin_amdgcn_mfma_f32_16x16x32_bf16(k1f, qf1[b], z, 0, 0, 0);
            }
            // p = exp2(s*scale*log2e + rpe*log2e); P^T -> Ps (packed b64)
            float psum;
            {
                float p0 = exp2f(fmaf(s0[0], 0.18033688f, rpl0.x));
                float p1 = exp2f(fmaf(s0[1], 0.18033688f, rpl0.y));
                float p2 = exp2f(fmaf(s0[2], 0.18033688f, rpl0.z));
                float p3 = exp2f(fmaf(s0[3], 0.18033688f, rpl0.w));
                psum = (p0 + p1) + (p2 + p3);
                *(ushort4*)&Ps[wave][b][c][quad * 4] =
                    make_ushort4(f2bf(p0), f2bf(p1), f2bf(p2), f2bf(p3));
            }
            {
                float p0 = exp2f(fmaf(s1[0], 0.18033688f, rpl1.x));
                float p1 = exp2f(fmaf(s1[1], 0.18033688f, rpl1.y));
                float p2 = exp2f(fmaf(s1[2], 0.18033688f, rpl1.z));
                float p3 = exp2f(fmaf(s1[3], 0.18033688f, rpl1.w));
                psum += (p0 + p1) + (p2 + p3);
                *(ushort4*)&Ps[wave][b][c][16 + quad * 4] =
                    make_ushort4(f2bf(p0), f2bf(p1), f2bf(p2), f2bf(p3));
            }
            l_i[b] += psum;
            // O += P V : K-dim 32, one MFMA per d-tile
            bf16x8 pa = *(const bf16x8*)&Ps[wave][b][c][quad * 8];
#pragma unroll
            for (int t = 0; t < 4; t++) {
                bf16x8 v0 = *(const bf16x8*)&Vs[b][16 * t + c][quad * 8];
                o_acc[b][t] = __builtin_amdgcn_mfma_f32_16x16x32_bf16(pa, v0, o_acc[b][t], 0, 0, 0);
            }
        }
        if (kt + 1 < kt1) { rpl0 = rpn0; rpl1 = rpn1; }
    }

    // ---- epilogue: reduce l over quads; store raw partials ----
#pragma unroll
    for (int b = 0; b < 2; b++) {
        const int rb = bp * 2 + b;
        float v = l_i[b];
        v += __shfl_xor(v, 16);
        v += __shfl_xor(v, 32);
        float* pob = po + (size_t)(ks * 32 + rb * H_ + h) * L_ * HD;
#pragma unroll
        for (int t = 0; t < 4; t++) {
            int d = 16 * t + c;
#pragma unroll
            for (int r = 0; r < 4; r++) {
                int l = rg0 + r;
                if (l < L_) pob[(size_t)l * HD + d] = o_acc[b][t][r];
            }
        }
        if (lane < 16) {
            float* lb = lsum + (size_t)(ks * 32 + rb * H_ + h) * LP;
            lb[r0w + lane] = v;
        }
    }
#undef LOAD_RPE
}

// -------------------------------------------------------------------------
// Merge: out[bh][d][l] = (po0+po1)[bh][l][d] / (l0+l1)[bh][l], LDS transpose.
// -------------------------------------------------------------------------
__global__ __launch_bounds__(256) void merge_kernel(
    const float* __restrict__ po, const float* __restrict__ lsum,
    float* __restrict__ out) {
    __shared__ __align__(16) float T[64][68];
    const int tid = threadIdx.x;
    const int bh = blockIdx.x >> 5;
    const int lt = blockIdx.x & 31;
    const float* p0 = po + (size_t)bh * L_ * HD;
    const float* p1 = p0 + (size_t)32 * L_ * HD;
    const float* ls0 = lsum + (size_t)bh * LP;
    const float* ls1 = ls0 + (size_t)32 * LP;
#pragma unroll
    for (int it = 0; it < 4; it++) {
        int idx = it * 256 + tid;
        int row = idx >> 4;
        int dc = (idx & 15) * 4;
        int l = lt * 64 + row;
        float4 v = make_float4(0.f, 0.f, 0.f, 0.f);
        if (l < L_) {
            float4 a  = *(const float4*)&p0[(size_t)l * HD + dc];
            float4 b4 = *(const float4*)&p1[(size_t)l * HD + dc];
            float inv = 1.f / (ls0[l] + ls1[l]);
            v = make_float4((a.x + b4.x) * inv, (a.y + b4.y) * inv,
                            (a.z + b4.z) * inv, (a.w + b4.w) * inv);
        }
        T[dc + 0][row] = v.x; T[dc + 1][row] = v.y;
        T[dc + 2][row] = v.z; T[dc + 3][row] = v.w;
    }
    __syncthreads();
    const int d = tid >> 2, ch = (tid & 3) * 16;
    const int lbase = lt * 64 + ch;
    if (lbase + 15 < L_) {
        float* dst = &out[((size_t)(bh * HD + d)) * L_ + lbase];
#pragma unroll
        for (int i = 0; i < 4; i++)
            *(float4*)&dst[4 * i] = *(const float4*)&T[d][ch + 4 * i];
    }
}

extern "C" void kernel_launch(void* const* d_in, const int* in_sizes, int n_in,
                              void* d_out, int out_size, void* d_ws, size_t ws_size,
                              hipStream_t stream) {
    const float* x   = (const float*)d_in[0];
    const float* rpe = (const float*)d_in[1];
    const float* Wq  = (const float*)d_in[2];
    const float* bq  = (const float*)d_in[3];
    const float* Wkv = (const float*)d_in[4];
    const float* bkv = (const float*)d_in[5];
    const float* Wl  = (const float*)d_in[6];
    const float* bl  = (const float*)d_in[7];
    float* out = (float*)d_out;

    unsigned short* wsu  = (unsigned short*)d_ws;
    unsigned short* x16  = wsu;                 // 4,096,000
    unsigned short* kv16 = wsu + 4096000;       // 4,096,000
    unsigned short* Wq16 = wsu + 8192000;       //   262,144
    unsigned short* Wkv16= wsu + 8454144;       //   524,288
    unsigned short* Q16  = wsu + 8978432;       // 4,194,304  [bh][2048][64]
    unsigned short* K16  = wsu + 13172736;      // 4,194,304  [bh][2048][64]
    unsigned short* V16  = wsu + 17367040;      // 4,194,304  [bh][64][2048]
    float* po   = (float*)(wsu + 21561344);     // 8,192,000 fp32 [2][32][2000][64]
    float* lsum = po + 8192000;                 //   131,072 fp32 [2][32][2048]

    conv_kernel<<<(B_ * L_ * C_ / 4 + 255) / 256, 256, 0, stream>>>(x, Wl, bl, kv16, x16);
    cvt_kernel<<<(786432 / 4 + 255) / 256, 256, 0, stream>>>(Wq, Wkv, Wq16, Wkv16);
    proj_mfma<<<dim3(125, 8), 256, 0, stream>>>(x16, Wq16, bq, Q16, nullptr, 0);
    proj_mfma<<<dim3(125, 16), 256, 0, stream>>>(kv16, Wkv16, bkv, K16, V16, 1);
    attn_mfma<<<1024, 256, 0, stream>>>(Q16, K16, V16, rpe, po, lsum);
    merge_kernel<<<1024, 256, 0, stream>>>(po, lsum, out);
}